// Round 8
// baseline (321.148 us; speedup 1.0000x reference)
//
#include <hip/hip_runtime.h>
#include <hip/hip_bf16.h>

#define DEVI __device__ __forceinline__

typedef float f32x4 __attribute__((ext_vector_type(4)));
typedef short s16x8 __attribute__((ext_vector_type(8)));

constexpr int T_ = 64;    // window
constexpr int F_ = 16;    // features
constexpr int H_ = 128;   // hidden
constexpr int NSEQ_ = 1024;
constexpr int NB_ = 16;   // sequences per block
constexpr int NBLK_ = NSEQ_ / NB_;  // 64 blocks

DEVI float sigmoidf_(float x) { return 1.0f / (1.0f + __expf(-x)); }
DEVI float tanhf_(float x) {
    float a = fabsf(x);
    float e = __expf(-2.0f * a);
    return copysignf((1.0f - e) / (1.0f + e), x);
}
DEVI ushort f2bf(float f) {             // fp32 -> bf16 bits, RNE
    unsigned u = __float_as_uint(f);
    return (ushort)((u + 0x7fffu + ((u >> 16) & 1u)) >> 16);
}
DEVI float bf2f(ushort b) { return __uint_as_float(((unsigned)b) << 16); }

#define MFMA16(A,B,C) __builtin_amdgcn_mfma_f32_16x16x32_bf16((A),(B),(C),0,0,0)

// LDS pool, phase-aliased (52752 B < 64 KB):
//  recurrence: hhA ushort[16][168] @0, hlA @5376, hhB @10752, hlB @16128 (end 21504)
//  epilogue:   w1bf ushort[128][140] @0 (35840)
//              a2s  float[16][128]  @35840 (8192)   [srbuf alias in E4+]
//              logitb float[16][64] @44032 (4096)
//              alph   float[16][64] @48128 (4096)
//              wab    float[132]    @52224 (528)
constexpr int POOL_BYTES = 52768;
constexpr int HSTR = 168;   // ushort stride per seq row (336 B -> conflict-free)

__global__ __launch_bounds__(512, 2)
void alphastock_main(const float* __restrict__ x,
                     const float* __restrict__ W_ih, const float* __restrict__ W_hh,
                     const float* __restrict__ b_ih, const float* __restrict__ b_hh,
                     const float* __restrict__ w1, const float* __restrict__ b1,
                     const float* __restrict__ w2, const float* __restrict__ b2,
                     const float* __restrict__ wa, const float* __restrict__ ba,
                     const float* __restrict__ wq, const float* __restrict__ bq,
                     const float* __restrict__ wk, const float* __restrict__ bk,
                     const float* __restrict__ wvm, const float* __restrict__ bv,
                     ushort* __restrict__ rep,   // [1024][64][128] bf16 ws
                     ushort* __restrict__ xgw,   // [1024][64][32] bf16 ws ([xhi;xhi])
                     float* __restrict__ qout, float* __restrict__ kout,
                     float* __restrict__ vout)
{
    __shared__ alignas(16) char pool_[POOL_BYTES];
    ushort* hhA   = (ushort*)pool_;
    ushort* hlA   = (ushort*)(pool_ + 5376);
    ushort* hhB   = (ushort*)(pool_ + 10752);
    ushort* hlB   = (ushort*)(pool_ + 16128);
    ushort* w1bf  = (ushort*)pool_;                    // [128][140] (epilogue)
    float*  a2s   = (float*)(pool_ + 35840);
    float*  logitb= (float*)(pool_ + 44032);
    float*  alph  = (float*)(pool_ + 48128);
    float*  wab   = (float*)(pool_ + 52224);

    const int tid  = threadIdx.x;
    const int wv   = tid >> 6;        // wave 0..7
    const int lane = tid & 63;
    const int lN   = lane & 15;       // frag col (seq) / A-row
    const int lK   = lane >> 4;       // k-group 0..3
    const int nb   = blockIdx.x * NB_;

    // ---- prologue: zero the t=0 read buffers; build xgw = [xhi;xhi] ----
    for (int i = tid; i < 10752 / 4; i += 512) ((unsigned*)pool_)[i] = 0;
    for (int idx = tid; idx < NB_ * T_ * F_; idx += 512) {   // 16384
        int s = idx >> 10, rem = idx & 1023;                 // rem = t*16+f
        int t = rem >> 4, f = rem & 15;
        ushort hb = f2bf(x[(size_t)(nb + s) * 1024 + rem]);
        size_t base = ((size_t)(nb + s) * T_ + t) * 32;
        xgw[base + f] = hb; xgw[base + 16 + f] = hb;
    }

    // ---- A-frags Whh hi/lo: row ra = 128g + 16wv + lN; k = ks*32 + lK*8 + i
    s16x8 ahi[4][4], alo[4][4];
    #pragma unroll
    for (int g = 0; g < 4; ++g) {
        const int ra = 128 * g + 16 * wv + lN;
        #pragma unroll
        for (int ks = 0; ks < 4; ++ks) {
            const float4* p = (const float4*)(W_hh + (size_t)ra * 128 + ks * 32 + lK * 8);
            float4 v0 = p[0], v1 = p[1];
            float w[8] = {v0.x,v0.y,v0.z,v0.w, v1.x,v1.y,v1.z,v1.w};
            #pragma unroll
            for (int i = 0; i < 8; ++i) {
                ushort hb = f2bf(w[i]);
                ahi[g][ks][i] = (short)hb;
                alo[g][ks][i] = (short)f2bf(w[i] - bf2f(hb));
            }
        }
    }
    // Wih k-packed frags: k<16 -> Wih_hi cols, k>=16 -> Wih_lo cols.
    // (paired with B=[xhi;xhi]: computes Whi@xhi + Wlo@xhi; Whi@xlo dropped ~1e-4)
    s16x8 wif[4];
    #pragma unroll
    for (int g = 0; g < 4; ++g) {
        const int ra = 128 * g + 16 * wv + lN;
        const float4* p = (const float4*)(W_ih + (size_t)ra * 16 + (lK & 1) * 8);
        float4 v0 = p[0], v1 = p[1];
        float w[8] = {v0.x,v0.y,v0.z,v0.w, v1.x,v1.y,v1.z,v1.w};
        #pragma unroll
        for (int i = 0; i < 8; ++i) {
            ushort hb = f2bf(w[i]);
            wif[g][i] = (short)((lK < 2) ? hb : f2bf(w[i] - bf2f(hb)));
        }
    }
    // bias folded into acc init: rows 128g + 16wv + 4lK + r
    f32x4 bias4[4];
    #pragma unroll
    for (int g = 0; g < 4; ++g)
        #pragma unroll
        for (int r = 0; r < 4; ++r) {
            int rr = 128 * g + 16 * wv + 4 * lK + r;
            bias4[g][r] = b_ih[rr] + b_hh[rr];
        }
    float cst[4] = {0.f, 0.f, 0.f, 0.f};
    __syncthreads();

    // ---- recurrent loop: ONE barrier/step, ping-pong h, bx prefetched ----
    const int hoff = lN * HSTR;
    const int jo   = 16 * wv + 4 * lK;
    const ushort* xgp = xgw + (size_t)(nb + lN) * T_ * 32 + lK * 8;
    s16x8 bx = *(const s16x8*)(xgp);              // t = 0
    int pp = 0;
    #pragma unroll 1
    for (int t = 0; t < T_; ++t) {
        const int tn = (t < 63) ? t + 1 : 63;
        s16x8 bxn = *(const s16x8*)(xgp + (size_t)tn * 32);   // prefetch t+1

        // acc init: bias + x-contribution (C-frag rows == acc rows by M-tile {8g+wv})
        f32x4 acc0 = MFMA16(wif[0], bx, bias4[0]);
        f32x4 acc1 = MFMA16(wif[1], bx, bias4[1]);
        f32x4 acc2 = MFMA16(wif[2], bx, bias4[2]);
        f32x4 acc3 = MFMA16(wif[3], bx, bias4[3]);

        const ushort* hh = pp ? hhB : hhA;
        const ushort* hl = pp ? hlB : hlA;
        #pragma unroll
        for (int ks = 0; ks < 4; ++ks) {
            s16x8 bh = *(const s16x8*)(hh + hoff + ks * 32 + lK * 8);
            s16x8 bl = *(const s16x8*)(hl + hoff + ks * 32 + lK * 8);
            acc0 = MFMA16(ahi[0][ks], bh, acc0); acc0 = MFMA16(ahi[0][ks], bl, acc0); acc0 = MFMA16(alo[0][ks], bh, acc0);
            acc1 = MFMA16(ahi[1][ks], bh, acc1); acc1 = MFMA16(ahi[1][ks], bl, acc1); acc1 = MFMA16(alo[1][ks], bh, acc1);
            acc2 = MFMA16(ahi[2][ks], bh, acc2); acc2 = MFMA16(ahi[2][ks], bl, acc2); acc2 = MFMA16(alo[2][ks], bh, acc2);
            acc3 = MFMA16(ahi[3][ks], bh, acc3); acc3 = MFMA16(ahi[3][ks], bl, acc3); acc3 = MFMA16(alo[3][ks], bh, acc3);
        }

        // cell update (i,f,g,o), pack h as bf16 hi/lo
        unsigned phx = 0, phy = 0, plx = 0, ply = 0;
        #pragma unroll
        for (int r = 0; r < 4; ++r) {
            float ii = sigmoidf_(acc0[r]);
            float ff = sigmoidf_(acc1[r]);
            float gg = tanhf_  (acc2[r]);
            float oo = sigmoidf_(acc3[r]);
            float c  = ff * cst[r] + ii * gg;
            cst[r] = c;
            float h  = oo * tanhf_(c);
            ushort hb = f2bf(h);
            ushort lb = f2bf(h - bf2f(hb));
            if      (r == 0) { phx = hb;                plx = lb; }
            else if (r == 1) { phx |= (unsigned)hb<<16; plx |= (unsigned)lb<<16; }
            else if (r == 2) { phy = hb;                ply = lb; }
            else             { phy |= (unsigned)hb<<16; ply |= (unsigned)lb<<16; }
        }
        uint2 uh; uh.x = phx; uh.y = phy;
        uint2 ul; ul.x = plx; ul.y = ply;
        ushort* hhw = pp ? hhA : hhB;          // write the OTHER buffer
        ushort* hlw = pp ? hlA : hlB;
        *(uint2*)(hhw + hoff + jo) = uh;
        *(uint2*)(hlw + hoff + jo) = ul;
        *(uint2*)(rep + ((size_t)(nb + lN) * T_ + t) * H_ + jo) = uh;
        bx = bxn;
        __syncthreads();
        pp ^= 1;
    }

    // ================= epilogue (16 seqs in this block) =================
    // E0: stage w1 (bf16, stride 140 for bank spread) + wa/ba
    for (int idx = tid; idx < 128 * 128; idx += 512) {
        int o = idx >> 7, k = idx & 127;
        w1bf[o * 140 + k] = f2bf(w1[idx]);
    }
    if (tid < 128) wab[tid] = wa[tid];
    if (tid == 128) wab[128] = ba[0];
    __syncthreads();

    // E1: a2[s][o] = h63 @ w2^T + b1 + b2   (wave 0 only)
    if (wv == 0) {
        s16x8 ar[4];
        #pragma unroll
        for (int ks = 0; ks < 4; ++ks)
            ar[ks] = *(const s16x8*)(rep + ((size_t)(nb + lN) * T_ + 63) * H_ + ks * 32 + lK * 8);
        #pragma unroll
        for (int nt = 0; nt < 8; ++nt) {
            f32x4 acc = {0.f,0.f,0.f,0.f};
            const int o = 16 * nt + lN;
            #pragma unroll
            for (int ks = 0; ks < 4; ++ks) {
                const float4* p = (const float4*)(w2 + (size_t)o * 128 + ks * 32 + lK * 8);
                float4 v0 = p[0], v1 = p[1];
                s16x8 bb;
                bb[0]=(short)f2bf(v0.x); bb[1]=(short)f2bf(v0.y); bb[2]=(short)f2bf(v0.z); bb[3]=(short)f2bf(v0.w);
                bb[4]=(short)f2bf(v1.x); bb[5]=(short)f2bf(v1.y); bb[6]=(short)f2bf(v1.z); bb[7]=(short)f2bf(v1.w);
                acc = MFMA16(ar[ks], bb, acc);
            }
            float bb12 = b1[o] + b2[o];
            #pragma unroll
            for (int r = 0; r < 4; ++r)
                a2s[(4 * lK + r) * 128 + o] = acc[r] + bb12;
        }
    }
    __syncthreads();

    // E2: logits[t] = sum_o wa[o] * tanh((rep @ w1^T)[t][o] + a2[o])
    #pragma unroll 1
    for (int sq = 0; sq < 2; ++sq) {
        const int seq = 2 * wv + sq;
        #pragma unroll 1
        for (int mt = 0; mt < 4; ++mt) {
            s16x8 ar[4];
            #pragma unroll
            for (int ks = 0; ks < 4; ++ks)
                ar[ks] = *(const s16x8*)(rep + ((size_t)(nb + seq) * T_ + 16 * mt + lN) * H_ + ks * 32 + lK * 8);
            float part[4] = {0.f,0.f,0.f,0.f};
            #pragma unroll
            for (int nt = 0; nt < 8; ++nt) {
                f32x4 acc = {0.f,0.f,0.f,0.f};
                #pragma unroll
                for (int ks = 0; ks < 4; ++ks)
                    acc = MFMA16(ar[ks],
                                 *(const s16x8*)(w1bf + (lN + 16 * nt) * 140 + ks * 32 + lK * 8),
                                 acc);
                const int o = lN + 16 * nt;
                const float wao = wab[o];
                const float a2o = a2s[seq * 128 + o];
                #pragma unroll
                for (int r = 0; r < 4; ++r)
                    part[r] += wao * tanhf_(acc[r] + a2o);
            }
            #pragma unroll
            for (int r = 0; r < 4; ++r) {
                part[r] += __shfl_xor(part[r], 1);
                part[r] += __shfl_xor(part[r], 2);
                part[r] += __shfl_xor(part[r], 4);
                part[r] += __shfl_xor(part[r], 8);
            }
            if (lN == 0) {
                float4 st; st.x = part[0]; st.y = part[1]; st.z = part[2]; st.w = part[3];
                *(float4*)(logitb + seq * 64 + 16 * mt + 4 * lK) = st;  // t = 16mt+4lK+r
            }
        }
    }
    __syncthreads();

    // E3: softmax over 64 logits, 2 seqs per wave
    #pragma unroll 1
    for (int sq = 0; sq < 2; ++sq) {
        const int seq = 2 * wv + sq;
        float vl = logitb[seq * 64 + lane] + wab[128];
        float m = vl;
        #pragma unroll
        for (int off = 1; off < 64; off <<= 1) m = fmaxf(m, __shfl_xor(m, off));
        float e = __expf(vl - m);
        float ss = e;
        #pragma unroll
        for (int off = 1; off < 64; off <<= 1) ss += __shfl_xor(ss, off);
        alph[seq * 64 + lane] = e / ss;
    }
    __syncthreads();

    // E4: stock_rep[s][h] = sum_t alpha * rep  (fp32, into a2s alias)
    {
        const int s = tid >> 5, hq = tid & 31;  // 4 h per thread
        float a0 = 0.f, a1 = 0.f, a2v = 0.f, a3 = 0.f;
        const ushort* rp = rep + (size_t)(nb + s) * T_ * H_ + hq * 4;
        for (int t = 0; t < T_; ++t) {
            float al = alph[s * 64 + t];
            uint2 rv = *(const uint2*)(rp + (size_t)t * H_);
            a0  += al * bf2f((ushort)(rv.x & 0xffff));
            a1  += al * bf2f((ushort)(rv.x >> 16));
            a2v += al * bf2f((ushort)(rv.y & 0xffff));
            a3  += al * bf2f((ushort)(rv.y >> 16));
        }
        float4 st; st.x = a0; st.y = a1; st.z = a2v; st.w = a3;
        __syncthreads();                       // a2s reads (E2) complete
        *(float4*)(a2s + s * 128 + hq * 4) = st;
    }
    __syncthreads();

    // E5: q,k,v = sr @ W^T + b  (fp32 VALU; bf16 here would poison CAAN softmax)
    {
        const float* sr = a2s;
        const int o = tid & 127, sg = tid >> 7;
        float aq[4] = {0,0,0,0}, ak[4] = {0,0,0,0}, av[4] = {0,0,0,0};
        for (int k = 0; k < 128; k += 4) {
            float4 q4 = *(const float4*)(wq  + (size_t)o * 128 + k);
            float4 k4 = *(const float4*)(wk  + (size_t)o * 128 + k);
            float4 v4 = *(const float4*)(wvm + (size_t)o * 128 + k);
            #pragma unroll
            for (int j = 0; j < 4; ++j) {
                float4 s4 = *(const float4*)(sr + (4 * sg + j) * 128 + k);
                aq[j] += q4.x*s4.x + q4.y*s4.y + q4.z*s4.z + q4.w*s4.w;
                ak[j] += k4.x*s4.x + k4.y*s4.y + k4.z*s4.z + k4.w*s4.w;
                av[j] += v4.x*s4.x + v4.y*s4.y + v4.z*s4.z + v4.w*s4.w;
            }
        }
        #pragma unroll
        for (int j = 0; j < 4; ++j) {
            const int s = 4 * sg + j;
            qout[(size_t)(nb + s) * H_ + o] = aq[j] + bq[o];
            kout[(size_t)(nb + s) * H_ + o] = ak[j] + bk[o];
            vout[(size_t)(nb + s) * H_ + o] = av[j] + bv[o];
        }
    }
}

// Cross-asset attention: one block per (b, m) query row, 256 threads. fp32 out.
__global__ __launch_bounds__(256, 4)
void caan(const float* __restrict__ qb, const float* __restrict__ kb,
          const float* __restrict__ vb, const float* __restrict__ ww,
          const float* __restrict__ bw, float* __restrict__ out)
{
    __shared__ alignas(16) float qs[H_];
    __shared__ alignas(16) float sc[512];
    __shared__ alignas(16) float red[8];
    __shared__ alignas(16) float pv[2][H_];

    const int n   = blockIdx.x;
    const int b   = n >> 9;
    const int tid = threadIdx.x;

    if (tid < H_) qs[tid] = qb[n * H_ + tid];
    __syncthreads();

    const float scale = 0.08838834764831845f;  // 1/sqrt(128)
    float s0raw = 0.f, s1raw = 0.f;
    #pragma unroll
    for (int r = 0; r < 2; ++r) {
        const int j = tid + r * 256;
        const float4* kp = (const float4*)(kb + (size_t)(b * 512 + j) * H_);
        const float4* qp = (const float4*)qs;
        float c0=0.f,c1=0.f,c2=0.f,c3=0.f;
        #pragma unroll
        for (int i = 0; i < 32; ++i) {
            float4 kv = kp[i], qv = qp[i];
            c0 += kv.x*qv.x; c1 += kv.y*qv.y; c2 += kv.z*qv.z; c3 += kv.w*qv.w;
        }
        float sres = ((c0 + c1) + (c2 + c3)) * scale;
        if (r == 0) s0raw = sres; else s1raw = sres;
    }

    float m = fmaxf(s0raw, s1raw);
    #pragma unroll
    for (int off = 1; off < 64; off <<= 1) m = fmaxf(m, __shfl_xor(m, off));
    if ((tid & 63) == 0) red[tid >> 6] = m;
    __syncthreads();
    m = fmaxf(fmaxf(red[0], red[1]), fmaxf(red[2], red[3]));
    float e0 = __expf(s0raw - m), e1 = __expf(s1raw - m);
    sc[tid] = e0; sc[tid + 256] = e1;
    float lsum = e0 + e1;
    #pragma unroll
    for (int off = 1; off < 64; off <<= 1) lsum += __shfl_xor(lsum, off);
    if ((tid & 63) == 0) red[4 + (tid >> 6)] = lsum;
    __syncthreads();
    const float inv = 1.0f / ((red[4] + red[5]) + (red[6] + red[7]));

    const int o  = tid & (H_ - 1);
    const int jh = tid >> 7;
    const float* vp = vb + (size_t)(b * 512 + jh * 256) * H_ + o;
    float a0=0.f,a1=0.f,a2=0.f,a3=0.f;
    for (int j = 0; j < 256; j += 4) {
        a0 += sc[jh*256 + j + 0] * vp[(size_t)(j + 0) * H_];
        a1 += sc[jh*256 + j + 1] * vp[(size_t)(j + 1) * H_];
        a2 += sc[jh*256 + j + 2] * vp[(size_t)(j + 2) * H_];
        a3 += sc[jh*256 + j + 3] * vp[(size_t)(j + 3) * H_];
    }
    pv[jh][o] = (a0 + a1) + (a2 + a3);
    __syncthreads();
    if (tid < H_) {
        float s = (pv[0][tid] + pv[1][tid]) * inv * ww[tid];
        s += __shfl_xor(s, 1);  s += __shfl_xor(s, 2);  s += __shfl_xor(s, 4);
        s += __shfl_xor(s, 8);  s += __shfl_xor(s, 16); s += __shfl_xor(s, 32);
        if ((tid & 63) == 0) red[tid >> 6] = s;
    }
    __syncthreads();
    if (tid == 0) out[n] = red[0] + red[1] + bw[0];
}

extern "C" void kernel_launch(void* const* d_in, const int* in_sizes, int n_in,
                              void* d_out, int out_size, void* d_ws, size_t ws_size,
                              hipStream_t stream)
{
    const float* x    = (const float*)d_in[0];
    const float* W_ih = (const float*)d_in[1];
    const float* W_hh = (const float*)d_in[2];
    const float* b_ih = (const float*)d_in[3];
    const float* b_hh = (const float*)d_in[4];
    const float* w1   = (const float*)d_in[5];
    const float* b1   = (const float*)d_in[6];
    const float* w2   = (const float*)d_in[7];
    const float* b2   = (const float*)d_in[8];
    const float* wa   = (const float*)d_in[9];
    const float* ba   = (const float*)d_in[10];
    const float* wq   = (const float*)d_in[11];
    const float* bq   = (const float*)d_in[12];
    const float* wk   = (const float*)d_in[13];
    const float* bk   = (const float*)d_in[14];
    const float* wv   = (const float*)d_in[15];
    const float* bv   = (const float*)d_in[16];
    const float* ww   = (const float*)d_in[17];
    const float* bw   = (const float*)d_in[18];

    float* ws   = (float*)d_ws;
    float* qbuf = ws;                              // 1024*128 f32
    float* kbuf = ws + (size_t)NSEQ_ * H_;
    float* vbuf = ws + (size_t)2 * NSEQ_ * H_;
    ushort* rep = (ushort*)(ws + (size_t)3 * NSEQ_ * H_);        // 16 MB bf16
    ushort* xgw = rep + (size_t)NSEQ_ * T_ * H_;                 // 4 MB bf16

    alphastock_main<<<NBLK_, 512, 0, stream>>>(x, W_ih, W_hh, b_ih, b_hh,
                                               w1, b1, w2, b2, wa, ba,
                                               wq, bq, wk, bk, wv, bv,
                                               rep, xgw, qbuf, kbuf, vbuf);
    caan<<<NSEQ_, 256, 0, stream>>>(qbuf, kbuf, vbuf, ww, bw, (float*)d_out);
}

// Round 9
// 313.204 us; speedup vs baseline: 1.0254x; 1.0254x over previous
//
#include <hip/hip_runtime.h>
#include <hip/hip_bf16.h>

#define DEVI __device__ __forceinline__

typedef float f32x4 __attribute__((ext_vector_type(4)));
typedef short s16x8 __attribute__((ext_vector_type(8)));

constexpr int T_ = 64;    // window
constexpr int F_ = 16;    // features
constexpr int H_ = 128;   // hidden
constexpr int NSEQ_ = 1024;
constexpr int NB_ = 16;   // sequences per block
constexpr int NBLK_ = NSEQ_ / NB_;  // 64 blocks

DEVI float sigmoidf_(float x) { return 1.0f / (1.0f + __expf(-x)); }
DEVI float tanhf_(float x) {
    float a = fabsf(x);
    float e = __expf(-2.0f * a);
    return copysignf((1.0f - e) / (1.0f + e), x);
}
DEVI ushort f2bf(float f) {             // fp32 -> bf16 bits, RNE
    unsigned u = __float_as_uint(f);
    return (ushort)((u + 0x7fffu + ((u >> 16) & 1u)) >> 16);
}
DEVI float bf2f(ushort b) { return __uint_as_float(((unsigned)b) << 16); }

#define MFMA16(A,B,C) __builtin_amdgcn_mfma_f32_16x16x32_bf16((A),(B),(C),0,0,0)

// LDS pool, phase-aliased (54544 B):
//  recurrence: xhi ushort[16][1032] @0 (33024B)   [x, bf16-hi, padded rows]
//              hhA @33024, hlA @38400, hhB @43776, hlB @49152 (each 5376B)
//  epilogue (all recurrence regions dead):
//              w1bf ushort[128][140] @0 (35840B)
//              a2s  float[16][128]  @35840
//              logitb float[16][64] @44032
//              alph   float[16][64] @48128
//              wab    float[132]    @52224
constexpr int XSTR = 1032;  // ushorts per x row (64*16 + 8 pad)
constexpr int HSTR = 168;   // ushorts per h row (336 B)
constexpr int OFF_HA  = 33024, OFF_HLA = 38400, OFF_HB = 43776, OFF_HLB = 49152;
constexpr int OFF_A2S = 35840, OFF_LOG = 44032, OFF_ALPH = 48128, OFF_WAB = 52224;
constexpr int POOL_BYTES = 54544;

__global__ __launch_bounds__(512, 2)
void alphastock_main(const float* __restrict__ x,
                     const float* __restrict__ W_ih, const float* __restrict__ W_hh,
                     const float* __restrict__ b_ih, const float* __restrict__ b_hh,
                     const float* __restrict__ w1, const float* __restrict__ b1,
                     const float* __restrict__ w2, const float* __restrict__ b2,
                     const float* __restrict__ wa, const float* __restrict__ ba,
                     const float* __restrict__ wq, const float* __restrict__ bq,
                     const float* __restrict__ wk, const float* __restrict__ bk,
                     const float* __restrict__ wvm, const float* __restrict__ bv,
                     ushort* __restrict__ rep,   // [1024][64][128] bf16 ws
                     float* __restrict__ qout, float* __restrict__ kout,
                     float* __restrict__ vout)
{
    __shared__ alignas(16) char pool_[POOL_BYTES];
    ushort* xhi   = (ushort*)pool_;
    ushort* hhA   = (ushort*)(pool_ + OFF_HA);
    ushort* hlA   = (ushort*)(pool_ + OFF_HLA);
    ushort* hhB   = (ushort*)(pool_ + OFF_HB);
    ushort* hlB   = (ushort*)(pool_ + OFF_HLB);
    ushort* w1bf  = (ushort*)pool_;                    // epilogue alias
    float*  a2s   = (float*)(pool_ + OFF_A2S);
    float*  logitb= (float*)(pool_ + OFF_LOG);
    float*  alph  = (float*)(pool_ + OFF_ALPH);
    float*  wab   = (float*)(pool_ + OFF_WAB);

    const int tid  = threadIdx.x;
    const int wv   = tid >> 6;        // wave 0..7
    const int lane = tid & 63;
    const int lN   = lane & 15;       // frag col (seq) / A-row
    const int lK   = lane >> 4;       // k-group 0..3
    const int nb   = blockIdx.x * NB_;

    // ---- prologue: zero t=0 h buffers (A); stage x -> LDS bf16-hi ----
    for (int i = tid; i < 10752 / 4; i += 512)
        ((unsigned*)(pool_ + OFF_HA))[i] = 0;          // hhA + hlA
    for (int idx = tid; idx < NB_ * T_ * F_; idx += 512) {   // 16384
        int s = idx >> 10, rem = idx & 1023;                 // rem = t*16+f
        xhi[s * XSTR + rem] = f2bf(x[(size_t)(nb + s) * 1024 + rem]);
    }

    // ---- A-frags Whh hi/lo: row ra = 128g + 16wv + lN; k = ks*32 + lK*8 + i
    s16x8 ahi[4][4], alo[4][4];
    #pragma unroll
    for (int g = 0; g < 4; ++g) {
        const int ra = 128 * g + 16 * wv + lN;
        #pragma unroll
        for (int ks = 0; ks < 4; ++ks) {
            const float4* p = (const float4*)(W_hh + (size_t)ra * 128 + ks * 32 + lK * 8);
            float4 v0 = p[0], v1 = p[1];
            float w[8] = {v0.x,v0.y,v0.z,v0.w, v1.x,v1.y,v1.z,v1.w};
            #pragma unroll
            for (int i = 0; i < 8; ++i) {
                ushort hb = f2bf(w[i]);
                ahi[g][ks][i] = (short)hb;
                alo[g][ks][i] = (short)f2bf(w[i] - bf2f(hb));
            }
        }
    }
    // Wih k-packed frags: lK<2 -> Wih_hi, lK>=2 -> Wih_lo (B supplies xhi twice
    // via (lK&1) addressing): computes (Whi+Wlo)@xhi.
    s16x8 wif[4];
    #pragma unroll
    for (int g = 0; g < 4; ++g) {
        const int ra = 128 * g + 16 * wv + lN;
        const float4* p = (const float4*)(W_ih + (size_t)ra * 16 + (lK & 1) * 8);
        float4 v0 = p[0], v1 = p[1];
        float w[8] = {v0.x,v0.y,v0.z,v0.w, v1.x,v1.y,v1.z,v1.w};
        #pragma unroll
        for (int i = 0; i < 8; ++i) {
            ushort hb = f2bf(w[i]);
            wif[g][i] = (short)((lK < 2) ? hb : f2bf(w[i] - bf2f(hb)));
        }
    }
    // bias folded into acc init: rows 128g + 16wv + 4lK + r
    f32x4 bias4[4];
    #pragma unroll
    for (int g = 0; g < 4; ++g)
        #pragma unroll
        for (int r = 0; r < 4; ++r) {
            int rr = 128 * g + 16 * wv + 4 * lK + r;
            bias4[g][r] = b_ih[rr] + b_hh[rr];
        }
    float cst[4] = {0.f, 0.f, 0.f, 0.f};
    __syncthreads();

    // ---- recurrent loop: NO global loads; rep stores batched per 4 steps ----
    const int hoff = lN * HSTR;
    const int jo   = 16 * wv + 4 * lK;
    const ushort* xrow = xhi + lN * XSTR + (lK & 1) * 8;
    uint2 rb0, rb1, rb2, rb3;
    #pragma unroll 1
    for (int tb = 0; tb < 16; ++tb) {
        #pragma unroll
        for (int u = 0; u < 4; ++u) {
            const int t = 4 * tb + u;
            s16x8 bx = *(const s16x8*)(xrow + t * 16);

            f32x4 acc0 = MFMA16(wif[0], bx, bias4[0]);
            f32x4 acc1 = MFMA16(wif[1], bx, bias4[1]);
            f32x4 acc2 = MFMA16(wif[2], bx, bias4[2]);
            f32x4 acc3 = MFMA16(wif[3], bx, bias4[3]);

            const ushort* hh = (u & 1) ? hhB : hhA;   // compile-time select
            const ushort* hl = (u & 1) ? hlB : hlA;
            #pragma unroll
            for (int ks = 0; ks < 4; ++ks) {
                s16x8 bh = *(const s16x8*)(hh + hoff + ks * 32 + lK * 8);
                s16x8 bl = *(const s16x8*)(hl + hoff + ks * 32 + lK * 8);
                acc0 = MFMA16(ahi[0][ks], bh, acc0); acc0 = MFMA16(ahi[0][ks], bl, acc0); acc0 = MFMA16(alo[0][ks], bh, acc0);
                acc1 = MFMA16(ahi[1][ks], bh, acc1); acc1 = MFMA16(ahi[1][ks], bl, acc1); acc1 = MFMA16(alo[1][ks], bh, acc1);
                acc2 = MFMA16(ahi[2][ks], bh, acc2); acc2 = MFMA16(ahi[2][ks], bl, acc2); acc2 = MFMA16(alo[2][ks], bh, acc2);
                acc3 = MFMA16(ahi[3][ks], bh, acc3); acc3 = MFMA16(ahi[3][ks], bl, acc3); acc3 = MFMA16(alo[3][ks], bh, acc3);
            }

            // cell update (i,f,g,o), pack h as bf16 hi/lo
            unsigned phx = 0, phy = 0, plx = 0, ply = 0;
            #pragma unroll
            for (int r = 0; r < 4; ++r) {
                float ii = sigmoidf_(acc0[r]);
                float ff = sigmoidf_(acc1[r]);
                float gg = tanhf_  (acc2[r]);
                float oo = sigmoidf_(acc3[r]);
                float c  = ff * cst[r] + ii * gg;
                cst[r] = c;
                float h  = oo * tanhf_(c);
                ushort hb = f2bf(h);
                ushort lb = f2bf(h - bf2f(hb));
                if      (r == 0) { phx = hb;                plx = lb; }
                else if (r == 1) { phx |= (unsigned)hb<<16; plx |= (unsigned)lb<<16; }
                else if (r == 2) { phy = hb;                ply = lb; }
                else             { phy |= (unsigned)hb<<16; ply |= (unsigned)lb<<16; }
            }
            uint2 uh; uh.x = phx; uh.y = phy;
            uint2 ul; ul.x = plx; ul.y = ply;
            ushort* hhw = (u & 1) ? hhA : hhB;        // write the OTHER buffer
            ushort* hlw = (u & 1) ? hlA : hlB;
            *(uint2*)(hhw + hoff + jo) = uh;
            *(uint2*)(hlw + hoff + jo) = ul;

            if      (u == 0) rb0 = uh;
            else if (u == 1) rb1 = uh;
            else if (u == 2) rb2 = uh;
            else {
                rb3 = uh;
                ushort* rp = rep + ((size_t)(nb + lN) * T_ + (t - 3)) * H_ + jo;
                *(uint2*)(rp)          = rb0;
                *(uint2*)(rp +   H_)   = rb1;
                *(uint2*)(rp + 2 * H_) = rb2;
                *(uint2*)(rp + 3 * H_) = rb3;
            }
            __syncthreads();
        }
    }

    // ================= epilogue (16 seqs in this block) =================
    // E0: stage w1 (bf16, stride 140) + wa/ba  (recurrence LDS dead)
    for (int idx = tid; idx < 128 * 128; idx += 512) {
        int o = idx >> 7, k = idx & 127;
        w1bf[o * 140 + k] = f2bf(w1[idx]);
    }
    if (tid < 128) wab[tid] = wa[tid];
    if (tid == 128) wab[128] = ba[0];
    __syncthreads();

    // E1: a2[s][o] = h63 @ w2^T + b1 + b2   (wave 0 only)
    if (wv == 0) {
        s16x8 ar[4];
        #pragma unroll
        for (int ks = 0; ks < 4; ++ks)
            ar[ks] = *(const s16x8*)(rep + ((size_t)(nb + lN) * T_ + 63) * H_ + ks * 32 + lK * 8);
        #pragma unroll
        for (int nt = 0; nt < 8; ++nt) {
            f32x4 acc = {0.f,0.f,0.f,0.f};
            const int o = 16 * nt + lN;
            #pragma unroll
            for (int ks = 0; ks < 4; ++ks) {
                const float4* p = (const float4*)(w2 + (size_t)o * 128 + ks * 32 + lK * 8);
                float4 v0 = p[0], v1 = p[1];
                s16x8 bb;
                bb[0]=(short)f2bf(v0.x); bb[1]=(short)f2bf(v0.y); bb[2]=(short)f2bf(v0.z); bb[3]=(short)f2bf(v0.w);
                bb[4]=(short)f2bf(v1.x); bb[5]=(short)f2bf(v1.y); bb[6]=(short)f2bf(v1.z); bb[7]=(short)f2bf(v1.w);
                acc = MFMA16(ar[ks], bb, acc);
            }
            float bb12 = b1[o] + b2[o];
            #pragma unroll
            for (int r = 0; r < 4; ++r)
                a2s[(4 * lK + r) * 128 + o] = acc[r] + bb12;
        }
    }
    __syncthreads();

    // E2: logits[t] = sum_o wa[o] * tanh((rep @ w1^T)[t][o] + a2[o])
    #pragma unroll 1
    for (int sq = 0; sq < 2; ++sq) {
        const int seq = 2 * wv + sq;
        #pragma unroll 1
        for (int mt = 0; mt < 4; ++mt) {
            s16x8 ar[4];
            #pragma unroll
            for (int ks = 0; ks < 4; ++ks)
                ar[ks] = *(const s16x8*)(rep + ((size_t)(nb + seq) * T_ + 16 * mt + lN) * H_ + ks * 32 + lK * 8);
            float part[4] = {0.f,0.f,0.f,0.f};
            #pragma unroll
            for (int nt = 0; nt < 8; ++nt) {
                f32x4 acc = {0.f,0.f,0.f,0.f};
                #pragma unroll
                for (int ks = 0; ks < 4; ++ks)
                    acc = MFMA16(ar[ks],
                                 *(const s16x8*)(w1bf + (lN + 16 * nt) * 140 + ks * 32 + lK * 8),
                                 acc);
                const int o = lN + 16 * nt;
                const float wao = wab[o];
                const float a2o = a2s[seq * 128 + o];
                #pragma unroll
                for (int r = 0; r < 4; ++r)
                    part[r] += wao * tanhf_(acc[r] + a2o);
            }
            #pragma unroll
            for (int r = 0; r < 4; ++r) {
                part[r] += __shfl_xor(part[r], 1);
                part[r] += __shfl_xor(part[r], 2);
                part[r] += __shfl_xor(part[r], 4);
                part[r] += __shfl_xor(part[r], 8);
            }
            if (lN == 0) {
                float4 st; st.x = part[0]; st.y = part[1]; st.z = part[2]; st.w = part[3];
                *(float4*)(logitb + seq * 64 + 16 * mt + 4 * lK) = st;  // t = 16mt+4lK+r
            }
        }
    }
    __syncthreads();

    // E3: softmax over 64 logits, 2 seqs per wave
    #pragma unroll 1
    for (int sq = 0; sq < 2; ++sq) {
        const int seq = 2 * wv + sq;
        float vl = logitb[seq * 64 + lane] + wab[128];
        float m = vl;
        #pragma unroll
        for (int off = 1; off < 64; off <<= 1) m = fmaxf(m, __shfl_xor(m, off));
        float e = __expf(vl - m);
        float ss = e;
        #pragma unroll
        for (int off = 1; off < 64; off <<= 1) ss += __shfl_xor(ss, off);
        alph[seq * 64 + lane] = e / ss;
    }
    __syncthreads();

    // E4: stock_rep[s][h] = sum_t alpha * rep  (fp32, into a2s alias)
    {
        const int s = tid >> 5, hq = tid & 31;  // 4 h per thread
        float a0 = 0.f, a1 = 0.f, a2v = 0.f, a3 = 0.f;
        const ushort* rp = rep + (size_t)(nb + s) * T_ * H_ + hq * 4;
        #pragma unroll 8
        for (int t = 0; t < T_; ++t) {
            float al = alph[s * 64 + t];
            uint2 rv = *(const uint2*)(rp + (size_t)t * H_);
            a0  += al * bf2f((ushort)(rv.x & 0xffff));
            a1  += al * bf2f((ushort)(rv.x >> 16));
            a2v += al * bf2f((ushort)(rv.y & 0xffff));
            a3  += al * bf2f((ushort)(rv.y >> 16));
        }
        float4 st; st.x = a0; st.y = a1; st.z = a2v; st.w = a3;
        __syncthreads();                       // a2s readers (E2) done
        *(float4*)(a2s + s * 128 + hq * 4) = st;
    }
    __syncthreads();

    // E5: q,k,v = sr @ W^T + b  (fp32 VALU; bf16 here would poison CAAN softmax)
    {
        const float* sr = a2s;
        const int o = tid & 127, sg = tid >> 7;
        float aq[4] = {0,0,0,0}, ak[4] = {0,0,0,0}, av[4] = {0,0,0,0};
        for (int k = 0; k < 128; k += 4) {
            float4 q4 = *(const float4*)(wq  + (size_t)o * 128 + k);
            float4 k4 = *(const float4*)(wk  + (size_t)o * 128 + k);
            float4 v4 = *(const float4*)(wvm + (size_t)o * 128 + k);
            #pragma unroll
            for (int j = 0; j < 4; ++j) {
                float4 s4 = *(const float4*)(sr + (4 * sg + j) * 128 + k);
                aq[j] += q4.x*s4.x + q4.y*s4.y + q4.z*s4.z + q4.w*s4.w;
                ak[j] += k4.x*s4.x + k4.y*s4.y + k4.z*s4.z + k4.w*s4.w;
                av[j] += v4.x*s4.x + v4.y*s4.y + v4.z*s4.z + v4.w*s4.w;
            }
        }
        #pragma unroll
        for (int j = 0; j < 4; ++j) {
            const int s = 4 * sg + j;
            qout[(size_t)(nb + s) * H_ + o] = aq[j] + bq[o];
            kout[(size_t)(nb + s) * H_ + o] = ak[j] + bk[o];
            vout[(size_t)(nb + s) * H_ + o] = av[j] + bv[o];
        }
    }
}

// Cross-asset attention: one block per (b, m) query row, 256 threads. fp32 out.
__global__ __launch_bounds__(256, 4)
void caan(const float* __restrict__ qb, const float* __restrict__ kb,
          const float* __restrict__ vb, const float* __restrict__ ww,
          const float* __restrict__ bw, float* __restrict__ out)
{
    __shared__ alignas(16) float qs[H_];
    __shared__ alignas(16) float sc[512];
    __shared__ alignas(16) float red[8];
    __shared__ alignas(16) float pv[2][H_];

    const int n   = blockIdx.x;
    const int b   = n >> 9;
    const int tid = threadIdx.x;

    if (tid < H_) qs[tid] = qb[n * H_ + tid];
    __syncthreads();

    const float scale = 0.08838834764831845f;  // 1/sqrt(128)
    float s0raw = 0.f, s1raw = 0.f;
    #pragma unroll
    for (int r = 0; r < 2; ++r) {
        const int j = tid + r * 256;
        const float4* kp = (const float4*)(kb + (size_t)(b * 512 + j) * H_);
        const float4* qp = (const float4*)qs;
        float c0=0.f,c1=0.f,c2=0.f,c3=0.f;
        #pragma unroll
        for (int i = 0; i < 32; ++i) {
            float4 kv = kp[i], qv = qp[i];
            c0 += kv.x*qv.x; c1 += kv.y*qv.y; c2 += kv.z*qv.z; c3 += kv.w*qv.w;
        }
        float sres = ((c0 + c1) + (c2 + c3)) * scale;
        if (r == 0) s0raw = sres; else s1raw = sres;
    }

    float m = fmaxf(s0raw, s1raw);
    #pragma unroll
    for (int off = 1; off < 64; off <<= 1) m = fmaxf(m, __shfl_xor(m, off));
    if ((tid & 63) == 0) red[tid >> 6] = m;
    __syncthreads();
    m = fmaxf(fmaxf(red[0], red[1]), fmaxf(red[2], red[3]));
    float e0 = __expf(s0raw - m), e1 = __expf(s1raw - m);
    sc[tid] = e0; sc[tid + 256] = e1;
    float lsum = e0 + e1;
    #pragma unroll
    for (int off = 1; off < 64; off <<= 1) lsum += __shfl_xor(lsum, off);
    if ((tid & 63) == 0) red[4 + (tid >> 6)] = lsum;
    __syncthreads();
    const float inv = 1.0f / ((red[4] + red[5]) + (red[6] + red[7]));

    const int o  = tid & (H_ - 1);
    const int jh = tid >> 7;
    const float* vp = vb + (size_t)(b * 512 + jh * 256) * H_ + o;
    float a0=0.f,a1=0.f,a2=0.f,a3=0.f;
    for (int j = 0; j < 256; j += 4) {
        a0 += sc[jh*256 + j + 0] * vp[(size_t)(j + 0) * H_];
        a1 += sc[jh*256 + j + 1] * vp[(size_t)(j + 1) * H_];
        a2 += sc[jh*256 + j + 2] * vp[(size_t)(j + 2) * H_];
        a3 += sc[jh*256 + j + 3] * vp[(size_t)(j + 3) * H_];
    }
    pv[jh][o] = (a0 + a1) + (a2 + a3);
    __syncthreads();
    if (tid < H_) {
        float s = (pv[0][tid] + pv[1][tid]) * inv * ww[tid];
        s += __shfl_xor(s, 1);  s += __shfl_xor(s, 2);  s += __shfl_xor(s, 4);
        s += __shfl_xor(s, 8);  s += __shfl_xor(s, 16); s += __shfl_xor(s, 32);
        if ((tid & 63) == 0) red[tid >> 6] = s;
    }
    __syncthreads();
    if (tid == 0) out[n] = red[0] + red[1] + bw[0];
}

extern "C" void kernel_launch(void* const* d_in, const int* in_sizes, int n_in,
                              void* d_out, int out_size, void* d_ws, size_t ws_size,
                              hipStream_t stream)
{
    const float* x    = (const float*)d_in[0];
    const float* W_ih = (const float*)d_in[1];
    const float* W_hh = (const float*)d_in[2];
    const float* b_ih = (const float*)d_in[3];
    const float* b_hh = (const float*)d_in[4];
    const float* w1   = (const float*)d_in[5];
    const float* b1   = (const float*)d_in[6];
    const float* w2   = (const float*)d_in[7];
    const float* b2   = (const float*)d_in[8];
    const float* wa   = (const float*)d_in[9];
    const float* ba   = (const float*)d_in[10];
    const float* wq   = (const float*)d_in[11];
    const float* bq   = (const float*)d_in[12];
    const float* wk   = (const float*)d_in[13];
    const float* bk   = (const float*)d_in[14];
    const float* wv   = (const float*)d_in[15];
    const float* bv   = (const float*)d_in[16];
    const float* ww   = (const float*)d_in[17];
    const float* bw   = (const float*)d_in[18];

    float* ws   = (float*)d_ws;
    float* qbuf = ws;                              // 1024*128 f32
    float* kbuf = ws + (size_t)NSEQ_ * H_;
    float* vbuf = ws + (size_t)2 * NSEQ_ * H_;
    ushort* rep = (ushort*)(ws + (size_t)3 * NSEQ_ * H_);        // 16 MB bf16

    alphastock_main<<<NBLK_, 512, 0, stream>>>(x, W_ih, W_hh, b_ih, b_hh,
                                               w1, b1, w2, b2, wa, ba,
                                               wq, bq, wk, bk, wv, bv,
                                               rep, qbuf, kbuf, vbuf);
    caan<<<NSEQ_, 256, 0, stream>>>(qbuf, kbuf, vbuf, ww, bw, (float*)d_out);
}

// Round 10
// 261.993 us; speedup vs baseline: 1.2258x; 1.1955x over previous
//
#include <hip/hip_runtime.h>
#include <hip/hip_bf16.h>

#define DEVI __device__ __forceinline__

typedef float f32x4 __attribute__((ext_vector_type(4)));
typedef short s16x8 __attribute__((ext_vector_type(8)));

constexpr int T_ = 64;    // window
constexpr int F_ = 16;    // features
constexpr int H_ = 128;   // hidden
constexpr int NSEQ_ = 1024;
constexpr int NB_ = 16;   // sequences per block
constexpr int NBLK_ = NSEQ_ / NB_;  // 64 blocks

DEVI float sigmoidf_(float x) { return 1.0f / (1.0f + __expf(-x)); }
DEVI float tanhf_(float x) {
    float a = fabsf(x);
    float e = __expf(-2.0f * a);
    return copysignf((1.0f - e) / (1.0f + e), x);
}
DEVI ushort f2h(float f) {              // fp32 -> fp16 bits
    _Float16 h = (_Float16)f;
    ushort b; __builtin_memcpy(&b, &h, 2); return b;
}
DEVI float h2f(ushort b) {
    _Float16 h; __builtin_memcpy(&h, &b, 2); return (float)h;
}

#define MFMA16(A,B,C) __builtin_amdgcn_mfma_f32_16x16x32_f16((A),(B),(C),0,0,0)

// LDS pool, phase-aliased (52768 B):
//  recurrence: xh ushort[16][1032] @0 (33024B)  [x fp16, padded rows]
//              hA @33024 (5376B), hB @38400 (5376B)   [h fp16 ping-pong]
//  epilogue (recurrence regions dead):
//              w1h ushort[128][140] @0 (35840B)
//              a2s  float[16][128]  @35840
//              logitb float[16][64] @44032
//              alph   float[16][64] @48128
//              wab    float[132]    @52224
constexpr int XSTR = 1032;
constexpr int HSTR = 168;   // f16 per h row (336 B)
constexpr int OFF_HA  = 33024, OFF_HB = 38400;
constexpr int OFF_A2S = 35840, OFF_LOG = 44032, OFF_ALPH = 48128, OFF_WAB = 52224;
constexpr int POOL_BYTES = 52768;

__global__ __launch_bounds__(512, 2)
void alphastock_main(const float* __restrict__ x,
                     const float* __restrict__ W_ih, const float* __restrict__ W_hh,
                     const float* __restrict__ b_ih, const float* __restrict__ b_hh,
                     const float* __restrict__ w1, const float* __restrict__ b1,
                     const float* __restrict__ w2, const float* __restrict__ b2,
                     const float* __restrict__ wa, const float* __restrict__ ba,
                     const float* __restrict__ wq, const float* __restrict__ bq,
                     const float* __restrict__ wk, const float* __restrict__ bk,
                     const float* __restrict__ wvm, const float* __restrict__ bv,
                     ushort* __restrict__ rep,   // [1024][64][128] fp16 ws
                     float* __restrict__ qout, float* __restrict__ kout,
                     float* __restrict__ vout)
{
    __shared__ alignas(16) char pool_[POOL_BYTES];
    ushort* xh    = (ushort*)pool_;
    ushort* hA    = (ushort*)(pool_ + OFF_HA);
    ushort* hB    = (ushort*)(pool_ + OFF_HB);
    ushort* w1h   = (ushort*)pool_;                    // epilogue alias
    float*  a2s   = (float*)(pool_ + OFF_A2S);
    float*  logitb= (float*)(pool_ + OFF_LOG);
    float*  alph  = (float*)(pool_ + OFF_ALPH);
    float*  wab   = (float*)(pool_ + OFF_WAB);

    const int tid  = threadIdx.x;
    const int wv   = tid >> 6;        // wave 0..7
    const int lane = tid & 63;
    const int lN   = lane & 15;       // frag col (seq) / A-row
    const int lK   = lane >> 4;       // k-group 0..3
    const int nb   = blockIdx.x * NB_;

    // ---- prologue: zero t=0 h buffer (A); stage x -> LDS fp16 ----
    for (int i = tid; i < 5376 / 4; i += 512)
        ((unsigned*)(pool_ + OFF_HA))[i] = 0;
    for (int idx = tid; idx < NB_ * T_ * F_; idx += 512) {   // 16384
        int s = idx >> 10, rem = idx & 1023;                 // rem = t*16+f
        xh[s * XSTR + rem] = f2h(x[(size_t)(nb + s) * 1024 + rem]);
    }

    // ---- A-frags Whh fp16: row ra = 128g + 16wv + lN; k = ks*32 + lK*8 + i
    s16x8 wf[4][4];
    #pragma unroll
    for (int g = 0; g < 4; ++g) {
        const int ra = 128 * g + 16 * wv + lN;
        #pragma unroll
        for (int ks = 0; ks < 4; ++ks) {
            const float4* p = (const float4*)(W_hh + (size_t)ra * 128 + ks * 32 + lK * 8);
            float4 v0 = p[0], v1 = p[1];
            float w[8] = {v0.x,v0.y,v0.z,v0.w, v1.x,v1.y,v1.z,v1.w};
            #pragma unroll
            for (int i = 0; i < 8; ++i) wf[g][ks][i] = (short)f2h(w[i]);
        }
    }
    // Wih fp16 frags: K=16 (features) padded to 32; lanes lK>=2 get zero A
    // (B supplies x twice via (lK&1) addressing, A zero kills the dup).
    s16x8 wif[4];
    #pragma unroll
    for (int g = 0; g < 4; ++g) {
        const int ra = 128 * g + 16 * wv + lN;
        const float4* p = (const float4*)(W_ih + (size_t)ra * 16 + (lK & 1) * 8);
        float4 v0 = p[0], v1 = p[1];
        float w[8] = {v0.x,v0.y,v0.z,v0.w, v1.x,v1.y,v1.z,v1.w};
        #pragma unroll
        for (int i = 0; i < 8; ++i)
            wif[g][i] = (short)((lK < 2) ? f2h(w[i]) : 0);
    }
    // bias folded into acc init: rows 128g + 16wv + 4lK + r
    f32x4 bias4[4];
    #pragma unroll
    for (int g = 0; g < 4; ++g)
        #pragma unroll
        for (int r = 0; r < 4; ++r) {
            int rr = 128 * g + 16 * wv + 4 * lK + r;
            bias4[g][r] = b_ih[rr] + b_hh[rr];
        }
    float cst[4] = {0.f, 0.f, 0.f, 0.f};
    __syncthreads();

    // ---- recurrent loop: 5-deep MFMA chain, 1 barrier/step, fp16 h ----
    const int hoff = lN * HSTR;
    const int jo   = 16 * wv + 4 * lK;
    const ushort* xrow = xh + lN * XSTR + (lK & 1) * 8;
    uint2 rb0, rb1, rb2, rb3;
    #pragma unroll 1
    for (int tb = 0; tb < 16; ++tb) {
        // prefetch the group's 4 x-fragments (xh is read-only during loop)
        s16x8 bx0 = *(const s16x8*)(xrow + (4 * tb + 0) * 16);
        s16x8 bx1 = *(const s16x8*)(xrow + (4 * tb + 1) * 16);
        s16x8 bx2 = *(const s16x8*)(xrow + (4 * tb + 2) * 16);
        s16x8 bx3 = *(const s16x8*)(xrow + (4 * tb + 3) * 16);
        #pragma unroll
        for (int u = 0; u < 4; ++u) {
            const int t = 4 * tb + u;
            s16x8 bx = (u == 0) ? bx0 : (u == 1) ? bx1 : (u == 2) ? bx2 : bx3;

            f32x4 acc0 = MFMA16(wif[0], bx, bias4[0]);
            f32x4 acc1 = MFMA16(wif[1], bx, bias4[1]);
            f32x4 acc2 = MFMA16(wif[2], bx, bias4[2]);
            f32x4 acc3 = MFMA16(wif[3], bx, bias4[3]);

            const ushort* hh = (u & 1) ? hB : hA;     // compile-time select
            #pragma unroll
            for (int ks = 0; ks < 4; ++ks) {
                s16x8 bh = *(const s16x8*)(hh + hoff + ks * 32 + lK * 8);
                acc0 = MFMA16(wf[0][ks], bh, acc0);
                acc1 = MFMA16(wf[1][ks], bh, acc1);
                acc2 = MFMA16(wf[2][ks], bh, acc2);
                acc3 = MFMA16(wf[3][ks], bh, acc3);
            }

            // cell update (i,f,g,o), pack h as fp16
            ushort hp[4];
            #pragma unroll
            for (int r = 0; r < 4; ++r) {
                float ii = sigmoidf_(acc0[r]);
                float ff = sigmoidf_(acc1[r]);
                float gg = tanhf_  (acc2[r]);
                float oo = sigmoidf_(acc3[r]);
                float c  = ff * cst[r] + ii * gg;
                cst[r] = c;
                hp[r] = f2h(oo * tanhf_(c));
            }
            uint2 uh;
            uh.x = (unsigned)hp[0] | ((unsigned)hp[1] << 16);
            uh.y = (unsigned)hp[2] | ((unsigned)hp[3] << 16);
            ushort* hw = (u & 1) ? hA : hB;           // write the OTHER buffer
            *(uint2*)(hw + hoff + jo) = uh;

            if      (u == 0) rb0 = uh;
            else if (u == 1) rb1 = uh;
            else if (u == 2) rb2 = uh;
            else {
                rb3 = uh;
                ushort* rp = rep + ((size_t)(nb + lN) * T_ + (t - 3)) * H_ + jo;
                *(uint2*)(rp)          = rb0;
                *(uint2*)(rp +   H_)   = rb1;
                *(uint2*)(rp + 2 * H_) = rb2;
                *(uint2*)(rp + 3 * H_) = rb3;
            }
            __syncthreads();
        }
    }

    // ================= epilogue (16 seqs in this block) =================
    // E0: stage w1 (fp16, stride 140) + wa/ba  (recurrence LDS dead)
    for (int idx = tid; idx < 128 * 128; idx += 512) {
        int o = idx >> 7, k = idx & 127;
        w1h[o * 140 + k] = f2h(w1[idx]);
    }
    if (tid < 128) wab[tid] = wa[tid];
    if (tid == 128) wab[128] = ba[0];
    __syncthreads();

    // E1: a2[s][o] = h63 @ w2^T + b1 + b2   (wave 0 only)
    if (wv == 0) {
        s16x8 ar[4];
        #pragma unroll
        for (int ks = 0; ks < 4; ++ks)
            ar[ks] = *(const s16x8*)(rep + ((size_t)(nb + lN) * T_ + 63) * H_ + ks * 32 + lK * 8);
        #pragma unroll
        for (int nt = 0; nt < 8; ++nt) {
            f32x4 acc = {0.f,0.f,0.f,0.f};
            const int o = 16 * nt + lN;
            #pragma unroll
            for (int ks = 0; ks < 4; ++ks) {
                const float4* p = (const float4*)(w2 + (size_t)o * 128 + ks * 32 + lK * 8);
                float4 v0 = p[0], v1 = p[1];
                s16x8 bb;
                bb[0]=(short)f2h(v0.x); bb[1]=(short)f2h(v0.y); bb[2]=(short)f2h(v0.z); bb[3]=(short)f2h(v0.w);
                bb[4]=(short)f2h(v1.x); bb[5]=(short)f2h(v1.y); bb[6]=(short)f2h(v1.z); bb[7]=(short)f2h(v1.w);
                acc = MFMA16(ar[ks], bb, acc);
            }
            float bb12 = b1[o] + b2[o];
            #pragma unroll
            for (int r = 0; r < 4; ++r)
                a2s[(4 * lK + r) * 128 + o] = acc[r] + bb12;
        }
    }
    __syncthreads();

    // E2: logits[t] = sum_o wa[o] * tanh((rep @ w1^T)[t][o] + a2[o])
    #pragma unroll 1
    for (int sq = 0; sq < 2; ++sq) {
        const int seq = 2 * wv + sq;
        #pragma unroll 1
        for (int mt = 0; mt < 4; ++mt) {
            s16x8 ar[4];
            #pragma unroll
            for (int ks = 0; ks < 4; ++ks)
                ar[ks] = *(const s16x8*)(rep + ((size_t)(nb + seq) * T_ + 16 * mt + lN) * H_ + ks * 32 + lK * 8);
            float part[4] = {0.f,0.f,0.f,0.f};
            #pragma unroll
            for (int nt = 0; nt < 8; ++nt) {
                f32x4 acc = {0.f,0.f,0.f,0.f};
                #pragma unroll
                for (int ks = 0; ks < 4; ++ks)
                    acc = MFMA16(ar[ks],
                                 *(const s16x8*)(w1h + (lN + 16 * nt) * 140 + ks * 32 + lK * 8),
                                 acc);
                const int o = lN + 16 * nt;
                const float wao = wab[o];
                const float a2o = a2s[seq * 128 + o];
                #pragma unroll
                for (int r = 0; r < 4; ++r)
                    part[r] += wao * tanhf_(acc[r] + a2o);
            }
            #pragma unroll
            for (int r = 0; r < 4; ++r) {
                part[r] += __shfl_xor(part[r], 1);
                part[r] += __shfl_xor(part[r], 2);
                part[r] += __shfl_xor(part[r], 4);
                part[r] += __shfl_xor(part[r], 8);
            }
            if (lN == 0) {
                float4 st; st.x = part[0]; st.y = part[1]; st.z = part[2]; st.w = part[3];
                *(float4*)(logitb + seq * 64 + 16 * mt + 4 * lK) = st;  // t = 16mt+4lK+r
            }
        }
    }
    __syncthreads();

    // E3: softmax over 64 logits, 2 seqs per wave
    #pragma unroll 1
    for (int sq = 0; sq < 2; ++sq) {
        const int seq = 2 * wv + sq;
        float vl = logitb[seq * 64 + lane] + wab[128];
        float m = vl;
        #pragma unroll
        for (int off = 1; off < 64; off <<= 1) m = fmaxf(m, __shfl_xor(m, off));
        float e = __expf(vl - m);
        float ss = e;
        #pragma unroll
        for (int off = 1; off < 64; off <<= 1) ss += __shfl_xor(ss, off);
        alph[seq * 64 + lane] = e / ss;
    }
    __syncthreads();

    // E4: stock_rep[s][h] = sum_t alpha * rep  (fp32, into a2s alias)
    {
        const int s = tid >> 5, hq = tid & 31;  // 4 h per thread
        float a0 = 0.f, a1 = 0.f, a2v = 0.f, a3 = 0.f;
        const ushort* rp = rep + (size_t)(nb + s) * T_ * H_ + hq * 4;
        #pragma unroll 8
        for (int t = 0; t < T_; ++t) {
            float al = alph[s * 64 + t];
            uint2 rv = *(const uint2*)(rp + (size_t)t * H_);
            a0  += al * h2f((ushort)(rv.x & 0xffff));
            a1  += al * h2f((ushort)(rv.x >> 16));
            a2v += al * h2f((ushort)(rv.y & 0xffff));
            a3  += al * h2f((ushort)(rv.y >> 16));
        }
        float4 st; st.x = a0; st.y = a1; st.z = a2v; st.w = a3;
        __syncthreads();                       // a2s readers (E2) done
        *(float4*)(a2s + s * 128 + hq * 4) = st;
    }
    __syncthreads();

    // E5: q,k,v = sr @ W^T + b  (fp32 VALU; bf16 here would poison CAAN softmax)
    {
        const float* sr = a2s;
        const int o = tid & 127, sg = tid >> 7;
        float aq[4] = {0,0,0,0}, ak[4] = {0,0,0,0}, av[4] = {0,0,0,0};
        for (int k = 0; k < 128; k += 4) {
            float4 q4 = *(const float4*)(wq  + (size_t)o * 128 + k);
            float4 k4 = *(const float4*)(wk  + (size_t)o * 128 + k);
            float4 v4 = *(const float4*)(wvm + (size_t)o * 128 + k);
            #pragma unroll
            for (int j = 0; j < 4; ++j) {
                float4 s4 = *(const float4*)(sr + (4 * sg + j) * 128 + k);
                aq[j] += q4.x*s4.x + q4.y*s4.y + q4.z*s4.z + q4.w*s4.w;
                ak[j] += k4.x*s4.x + k4.y*s4.y + k4.z*s4.z + k4.w*s4.w;
                av[j] += v4.x*s4.x + v4.y*s4.y + v4.z*s4.z + v4.w*s4.w;
            }
        }
        #pragma unroll
        for (int j = 0; j < 4; ++j) {
            const int s = 4 * sg + j;
            qout[(size_t)(nb + s) * H_ + o] = aq[j] + bq[o];
            kout[(size_t)(nb + s) * H_ + o] = ak[j] + bk[o];
            vout[(size_t)(nb + s) * H_ + o] = av[j] + bv[o];
        }
    }
}

// Cross-asset attention: one block per (b, m) query row, 256 threads. fp32 out.
__global__ __launch_bounds__(256, 4)
void caan(const float* __restrict__ qb, const float* __restrict__ kb,
          const float* __restrict__ vb, const float* __restrict__ ww,
          const float* __restrict__ bw, float* __restrict__ out)
{
    __shared__ alignas(16) float qs[H_];
    __shared__ alignas(16) float sc[512];
    __shared__ alignas(16) float red[8];
    __shared__ alignas(16) float pv[2][H_];

    const int n   = blockIdx.x;
    const int b   = n >> 9;
    const int tid = threadIdx.x;

    if (tid < H_) qs[tid] = qb[n * H_ + tid];
    __syncthreads();

    const float scale = 0.08838834764831845f;  // 1/sqrt(128)
    float s0raw = 0.f, s1raw = 0.f;
    #pragma unroll
    for (int r = 0; r < 2; ++r) {
        const int j = tid + r * 256;
        const float4* kp = (const float4*)(kb + (size_t)(b * 512 + j) * H_);
        const float4* qp = (const float4*)qs;
        float c0=0.f,c1=0.f,c2=0.f,c3=0.f;
        #pragma unroll
        for (int i = 0; i < 32; ++i) {
            float4 kv = kp[i], qv = qp[i];
            c0 += kv.x*qv.x; c1 += kv.y*qv.y; c2 += kv.z*qv.z; c3 += kv.w*qv.w;
        }
        float sres = ((c0 + c1) + (c2 + c3)) * scale;
        if (r == 0) s0raw = sres; else s1raw = sres;
    }

    float m = fmaxf(s0raw, s1raw);
    #pragma unroll
    for (int off = 1; off < 64; off <<= 1) m = fmaxf(m, __shfl_xor(m, off));
    if ((tid & 63) == 0) red[tid >> 6] = m;
    __syncthreads();
    m = fmaxf(fmaxf(red[0], red[1]), fmaxf(red[2], red[3]));
    float e0 = __expf(s0raw - m), e1 = __expf(s1raw - m);
    sc[tid] = e0; sc[tid + 256] = e1;
    float lsum = e0 + e1;
    #pragma unroll
    for (int off = 1; off < 64; off <<= 1) lsum += __shfl_xor(lsum, off);
    if ((tid & 63) == 0) red[4 + (tid >> 6)] = lsum;
    __syncthreads();
    const float inv = 1.0f / ((red[4] + red[5]) + (red[6] + red[7]));

    const int o  = tid & (H_ - 1);
    const int jh = tid >> 7;
    const float* vp = vb + (size_t)(b * 512 + jh * 256) * H_ + o;
    float a0=0.f,a1=0.f,a2=0.f,a3=0.f;
    for (int j = 0; j < 256; j += 4) {
        a0 += sc[jh*256 + j + 0] * vp[(size_t)(j + 0) * H_];
        a1 += sc[jh*256 + j + 1] * vp[(size_t)(j + 1) * H_];
        a2 += sc[jh*256 + j + 2] * vp[(size_t)(j + 2) * H_];
        a3 += sc[jh*256 + j + 3] * vp[(size_t)(j + 3) * H_];
    }
    pv[jh][o] = (a0 + a1) + (a2 + a3);
    __syncthreads();
    if (tid < H_) {
        float s = (pv[0][tid] + pv[1][tid]) * inv * ww[tid];
        s += __shfl_xor(s, 1);  s += __shfl_xor(s, 2);  s += __shfl_xor(s, 4);
        s += __shfl_xor(s, 8);  s += __shfl_xor(s, 16); s += __shfl_xor(s, 32);
        if ((tid & 63) == 0) red[tid >> 6] = s;
    }
    __syncthreads();
    if (tid == 0) out[n] = red[0] + red[1] + bw[0];
}

extern "C" void kernel_launch(void* const* d_in, const int* in_sizes, int n_in,
                              void* d_out, int out_size, void* d_ws, size_t ws_size,
                              hipStream_t stream)
{
    const float* x    = (const float*)d_in[0];
    const float* W_ih = (const float*)d_in[1];
    const float* W_hh = (const float*)d_in[2];
    const float* b_ih = (const float*)d_in[3];
    const float* b_hh = (const float*)d_in[4];
    const float* w1   = (const float*)d_in[5];
    const float* b1   = (const float*)d_in[6];
    const float* w2   = (const float*)d_in[7];
    const float* b2   = (const float*)d_in[8];
    const float* wa   = (const float*)d_in[9];
    const float* ba   = (const float*)d_in[10];
    const float* wq   = (const float*)d_in[11];
    const float* bq   = (const float*)d_in[12];
    const float* wk   = (const float*)d_in[13];
    const float* bk   = (const float*)d_in[14];
    const float* wv   = (const float*)d_in[15];
    const float* bv   = (const float*)d_in[16];
    const float* ww   = (const float*)d_in[17];
    const float* bw   = (const float*)d_in[18];

    float* ws   = (float*)d_ws;
    float* qbuf = ws;                              // 1024*128 f32
    float* kbuf = ws + (size_t)NSEQ_ * H_;
    float* vbuf = ws + (size_t)2 * NSEQ_ * H_;
    ushort* rep = (ushort*)(ws + (size_t)3 * NSEQ_ * H_);        // 16 MB fp16

    alphastock_main<<<NBLK_, 512, 0, stream>>>(x, W_ih, W_hh, b_ih, b_hh,
                                               w1, b1, w2, b2, wa, ba,
                                               wq, bq, wk, bk, wv, bv,
                                               rep, qbuf, kbuf, vbuf);
    caan<<<NSEQ_, 256, 0, stream>>>(qbuf, kbuf, vbuf, ww, bw, (float*)d_out);
}

// Round 11
// 216.450 us; speedup vs baseline: 1.4837x; 1.2104x over previous
//
#include <hip/hip_runtime.h>
#include <hip/hip_bf16.h>

#define DEVI __device__ __forceinline__

typedef float f32x4 __attribute__((ext_vector_type(4)));
typedef short s16x8 __attribute__((ext_vector_type(8)));

constexpr int T_ = 64;    // window
constexpr int F_ = 16;    // features
constexpr int H_ = 128;   // hidden
constexpr int NSEQ_ = 1024;
constexpr int NB_ = 4;    // sequences per block (MFMA N cols 4..15 don't-care)
constexpr int NBLK_ = NSEQ_ / NB_;  // 256 blocks -> every CU gets work

DEVI float sigmoidf_(float x) { return 1.0f / (1.0f + __expf(-x)); }
DEVI float tanhf_(float x) {
    float a = fabsf(x);
    float e = __expf(-2.0f * a);
    return copysignf((1.0f - e) / (1.0f + e), x);
}
DEVI ushort f2h(float f) {              // fp32 -> fp16 bits
    _Float16 h = (_Float16)f;
    ushort b; __builtin_memcpy(&b, &h, 2); return b;
}
DEVI float h2f(ushort b) {
    _Float16 h; __builtin_memcpy(&h, &b, 2); return (float)h;
}

#define MFMA16(A,B,C) __builtin_amdgcn_mfma_f32_16x16x32_f16((A),(B),(C),0,0,0)

// LDS pool, phase-aliased (52768 B):
//  recurrence: xh ushort[4][1032] @0 (8256B)  [x fp16, 4 real seqs]
//              hA @8320 (5376B), hB @13696 (5376B)   [h fp16 ping-pong, 16 cols]
//  epilogue (recurrence regions dead):
//              w1h ushort[128][140] @0 (35840B)
//              a2s  float[16][128]  @35840
//              logitb float[16][64] @44032
//              alph   float[16][64] @48128
//              wab    float[132]    @52224
constexpr int XSTR = 1032;
constexpr int HSTR = 168;   // f16 per h row (336 B)
constexpr int OFF_HA  = 8320, OFF_HB = 13696;
constexpr int OFF_A2S = 35840, OFF_LOG = 44032, OFF_ALPH = 48128, OFF_WAB = 52224;
constexpr int POOL_BYTES = 52768;

__global__ __launch_bounds__(512, 2)
void alphastock_main(const float* __restrict__ x,
                     const float* __restrict__ W_ih, const float* __restrict__ W_hh,
                     const float* __restrict__ b_ih, const float* __restrict__ b_hh,
                     const float* __restrict__ w1, const float* __restrict__ b1,
                     const float* __restrict__ w2, const float* __restrict__ b2,
                     const float* __restrict__ wa, const float* __restrict__ ba,
                     const float* __restrict__ wq, const float* __restrict__ bq,
                     const float* __restrict__ wk, const float* __restrict__ bk,
                     const float* __restrict__ wvm, const float* __restrict__ bv,
                     ushort* __restrict__ rep,   // [1024][64][128] fp16 ws
                     float* __restrict__ qout, float* __restrict__ kout,
                     float* __restrict__ vout)
{
    __shared__ alignas(16) char pool_[POOL_BYTES];
    ushort* xh    = (ushort*)pool_;
    ushort* hA    = (ushort*)(pool_ + OFF_HA);
    ushort* hB    = (ushort*)(pool_ + OFF_HB);
    ushort* w1h   = (ushort*)pool_;                    // epilogue alias
    float*  a2s   = (float*)(pool_ + OFF_A2S);
    float*  logitb= (float*)(pool_ + OFF_LOG);
    float*  alph  = (float*)(pool_ + OFF_ALPH);
    float*  wab   = (float*)(pool_ + OFF_WAB);

    const int tid  = threadIdx.x;
    const int wv   = tid >> 6;        // wave 0..7
    const int lane = tid & 63;
    const int lN   = lane & 15;       // frag col (seq; real 0..3) / A-row
    const int lK   = lane >> 4;       // k-group 0..3
    const int nb   = blockIdx.x * NB_;

    // ---- prologue: zero t=0 h buffer (A); stage x (4 seqs) -> LDS fp16 ----
    for (int i = tid; i < 5376 / 4; i += 512)
        ((unsigned*)(pool_ + OFF_HA))[i] = 0;
    for (int idx = tid; idx < NB_ * T_ * F_; idx += 512) {   // 4096
        int s = idx >> 10, rem = idx & 1023;                 // rem = t*16+f
        xh[s * XSTR + rem] = f2h(x[(size_t)(nb + s) * 1024 + rem]);
    }

    // ---- A-frags Whh fp16: row ra = 128g + 16wv + lN; k = ks*32 + lK*8 + i
    s16x8 wf[4][4];
    #pragma unroll
    for (int g = 0; g < 4; ++g) {
        const int ra = 128 * g + 16 * wv + lN;
        #pragma unroll
        for (int ks = 0; ks < 4; ++ks) {
            const float4* p = (const float4*)(W_hh + (size_t)ra * 128 + ks * 32 + lK * 8);
            float4 v0 = p[0], v1 = p[1];
            float w[8] = {v0.x,v0.y,v0.z,v0.w, v1.x,v1.y,v1.z,v1.w};
            #pragma unroll
            for (int i = 0; i < 8; ++i) wf[g][ks][i] = (short)f2h(w[i]);
        }
    }
    // Wih fp16 frags: K=16 padded to 32; lanes lK>=2 get zero A.
    s16x8 wif[4];
    #pragma unroll
    for (int g = 0; g < 4; ++g) {
        const int ra = 128 * g + 16 * wv + lN;
        const float4* p = (const float4*)(W_ih + (size_t)ra * 16 + (lK & 1) * 8);
        float4 v0 = p[0], v1 = p[1];
        float w[8] = {v0.x,v0.y,v0.z,v0.w, v1.x,v1.y,v1.z,v1.w};
        #pragma unroll
        for (int i = 0; i < 8; ++i)
            wif[g][i] = (short)((lK < 2) ? f2h(w[i]) : 0);
    }
    // bias folded into acc init: rows 128g + 16wv + 4lK + r
    f32x4 bias4[4];
    #pragma unroll
    for (int g = 0; g < 4; ++g)
        #pragma unroll
        for (int r = 0; r < 4; ++r) {
            int rr = 128 * g + 16 * wv + 4 * lK + r;
            bias4[g][r] = b_ih[rr] + b_hh[rr];
        }
    float cst[4] = {0.f, 0.f, 0.f, 0.f};
    __syncthreads();

    // ---- recurrent loop: 5-deep MFMA chain, 1 barrier/step, fp16 h ----
    // Lanes lN>=4 run duplicate chains of seq lN&3 (finite, column-confined).
    const int hoff = lN * HSTR;
    const int jo   = 16 * wv + 4 * lK;
    const ushort* xrow = xh + (lN & 3) * XSTR + (lK & 1) * 8;
    uint2 rb0, rb1, rb2, rb3;
    #pragma unroll 1
    for (int tb = 0; tb < 16; ++tb) {
        s16x8 bx0 = *(const s16x8*)(xrow + (4 * tb + 0) * 16);
        s16x8 bx1 = *(const s16x8*)(xrow + (4 * tb + 1) * 16);
        s16x8 bx2 = *(const s16x8*)(xrow + (4 * tb + 2) * 16);
        s16x8 bx3 = *(const s16x8*)(xrow + (4 * tb + 3) * 16);
        #pragma unroll
        for (int u = 0; u < 4; ++u) {
            const int t = 4 * tb + u;
            s16x8 bx = (u == 0) ? bx0 : (u == 1) ? bx1 : (u == 2) ? bx2 : bx3;

            f32x4 acc0 = MFMA16(wif[0], bx, bias4[0]);
            f32x4 acc1 = MFMA16(wif[1], bx, bias4[1]);
            f32x4 acc2 = MFMA16(wif[2], bx, bias4[2]);
            f32x4 acc3 = MFMA16(wif[3], bx, bias4[3]);

            const ushort* hh = (u & 1) ? hB : hA;     // compile-time select
            #pragma unroll
            for (int ks = 0; ks < 4; ++ks) {
                s16x8 bh = *(const s16x8*)(hh + hoff + ks * 32 + lK * 8);
                acc0 = MFMA16(wf[0][ks], bh, acc0);
                acc1 = MFMA16(wf[1][ks], bh, acc1);
                acc2 = MFMA16(wf[2][ks], bh, acc2);
                acc3 = MFMA16(wf[3][ks], bh, acc3);
            }

            // cell update (i,f,g,o), pack h as fp16
            ushort hp[4];
            #pragma unroll
            for (int r = 0; r < 4; ++r) {
                float ii = sigmoidf_(acc0[r]);
                float ff = sigmoidf_(acc1[r]);
                float gg = tanhf_  (acc2[r]);
                float oo = sigmoidf_(acc3[r]);
                float c  = ff * cst[r] + ii * gg;
                cst[r] = c;
                hp[r] = f2h(oo * tanhf_(c));
            }
            uint2 uh;
            uh.x = (unsigned)hp[0] | ((unsigned)hp[1] << 16);
            uh.y = (unsigned)hp[2] | ((unsigned)hp[3] << 16);
            ushort* hw = (u & 1) ? hA : hB;           // write the OTHER buffer
            *(uint2*)(hw + hoff + jo) = uh;

            if      (u == 0) rb0 = uh;
            else if (u == 1) rb1 = uh;
            else if (u == 2) rb2 = uh;
            else {
                rb3 = uh;
                if (lN < NB_) {                       // real seqs only
                    ushort* rp = rep + ((size_t)(nb + lN) * T_ + (t - 3)) * H_ + jo;
                    *(uint2*)(rp)          = rb0;
                    *(uint2*)(rp +   H_)   = rb1;
                    *(uint2*)(rp + 2 * H_) = rb2;
                    *(uint2*)(rp + 3 * H_) = rb3;
                }
            }
            __syncthreads();
        }
    }

    // ================= epilogue (4 seqs in this block) =================
    // E0: stage w1 (fp16, stride 140) + wa/ba  (recurrence LDS dead)
    for (int idx = tid; idx < 128 * 128; idx += 512) {
        int o = idx >> 7, k = idx & 127;
        w1h[o * 140 + k] = f2h(w1[idx]);
    }
    if (tid < 128) wab[tid] = wa[tid];
    if (tid == 128) wab[128] = ba[0];
    __syncthreads();

    // E1: a2[s][o] = h63 @ w2^T + b1 + b2  (wave 0; A rows >=4 are dup/garbage,
    // D row m uses only A row m -> rows 0..3 correct; pointer clamped in-bounds)
    if (wv == 0) {
        s16x8 ar[4];
        #pragma unroll
        for (int ks = 0; ks < 4; ++ks)
            ar[ks] = *(const s16x8*)(rep + ((size_t)(nb + (lN & 3)) * T_ + 63) * H_ + ks * 32 + lK * 8);
        #pragma unroll
        for (int nt = 0; nt < 8; ++nt) {
            f32x4 acc = {0.f,0.f,0.f,0.f};
            const int o = 16 * nt + lN;
            #pragma unroll
            for (int ks = 0; ks < 4; ++ks) {
                const float4* p = (const float4*)(w2 + (size_t)o * 128 + ks * 32 + lK * 8);
                float4 v0 = p[0], v1 = p[1];
                s16x8 bb;
                bb[0]=(short)f2h(v0.x); bb[1]=(short)f2h(v0.y); bb[2]=(short)f2h(v0.z); bb[3]=(short)f2h(v0.w);
                bb[4]=(short)f2h(v1.x); bb[5]=(short)f2h(v1.y); bb[6]=(short)f2h(v1.z); bb[7]=(short)f2h(v1.w);
                acc = MFMA16(ar[ks], bb, acc);
            }
            float bb12 = b1[o] + b2[o];
            #pragma unroll
            for (int r = 0; r < 4; ++r)
                a2s[(4 * lK + r) * 128 + o] = acc[r] + bb12;   // seq = 4lK+r
        }
    }
    __syncthreads();

    // E2: logits[t] = sum_o wa[o]*tanh((rep @ w1^T)[t][o] + a2[o])
    // 2 waves per seq: seq = wv>>1, mt = (wv&1)*2 + mtl
    {
        const int seq = wv >> 1;
        #pragma unroll 1
        for (int mtl = 0; mtl < 2; ++mtl) {
            const int mt = (wv & 1) * 2 + mtl;
            s16x8 ar[4];
            #pragma unroll
            for (int ks = 0; ks < 4; ++ks)
                ar[ks] = *(const s16x8*)(rep + ((size_t)(nb + seq) * T_ + 16 * mt + lN) * H_ + ks * 32 + lK * 8);
            float part[4] = {0.f,0.f,0.f,0.f};
            #pragma unroll
            for (int nt = 0; nt < 8; ++nt) {
                f32x4 acc = {0.f,0.f,0.f,0.f};
                #pragma unroll
                for (int ks = 0; ks < 4; ++ks)
                    acc = MFMA16(ar[ks],
                                 *(const s16x8*)(w1h + (lN + 16 * nt) * 140 + ks * 32 + lK * 8),
                                 acc);
                const int o = lN + 16 * nt;
                const float wao = wab[o];
                const float a2o = a2s[seq * 128 + o];
                #pragma unroll
                for (int r = 0; r < 4; ++r)
                    part[r] += wao * tanhf_(acc[r] + a2o);
            }
            #pragma unroll
            for (int r = 0; r < 4; ++r) {
                part[r] += __shfl_xor(part[r], 1);
                part[r] += __shfl_xor(part[r], 2);
                part[r] += __shfl_xor(part[r], 4);
                part[r] += __shfl_xor(part[r], 8);
            }
            if (lN == 0) {
                float4 st; st.x = part[0]; st.y = part[1]; st.z = part[2]; st.w = part[3];
                *(float4*)(logitb + seq * 64 + 16 * mt + 4 * lK) = st;  // t = 16mt+4lK+r
            }
        }
    }
    __syncthreads();

    // E3: softmax over 64 logits, seq = wv (waves 0..3)
    if (wv < NB_) {
        const int seq = wv;
        float vl = logitb[seq * 64 + lane] + wab[128];
        float m = vl;
        #pragma unroll
        for (int off = 1; off < 64; off <<= 1) m = fmaxf(m, __shfl_xor(m, off));
        float e = __expf(vl - m);
        float ss = e;
        #pragma unroll
        for (int off = 1; off < 64; off <<= 1) ss += __shfl_xor(ss, off);
        alph[seq * 64 + lane] = e / ss;
    }
    __syncthreads();

    // E4: stock_rep[s][h] = sum_t alpha * rep  (fp32, into a2s alias)
    {
        const int s = tid >> 7, o = tid & 127;     // 1 element per thread
        float acc = 0.f;
        const ushort* rp = rep + (size_t)(nb + s) * T_ * H_ + o;
        #pragma unroll 8
        for (int t = 0; t < T_; ++t)
            acc += alph[s * 64 + t] * h2f(rp[(size_t)t * H_]);
        __syncthreads();                           // a2s readers (E2) done
        a2s[s * 128 + o] = acc;
    }
    __syncthreads();

    // E5: q,k,v = sr @ W^T + b  (fp32 VALU; one seq per thread-group)
    {
        const float* sr = a2s;
        const int o = tid & 127, sg = tid >> 7;    // sg = seq 0..3
        float aq = 0.f, ak = 0.f, av = 0.f;
        for (int k = 0; k < 128; k += 4) {
            float4 q4 = *(const float4*)(wq  + (size_t)o * 128 + k);
            float4 k4 = *(const float4*)(wk  + (size_t)o * 128 + k);
            float4 v4 = *(const float4*)(wvm + (size_t)o * 128 + k);
            float4 s4 = *(const float4*)(sr + sg * 128 + k);
            aq += q4.x*s4.x + q4.y*s4.y + q4.z*s4.z + q4.w*s4.w;
            ak += k4.x*s4.x + k4.y*s4.y + k4.z*s4.z + k4.w*s4.w;
            av += v4.x*s4.x + v4.y*s4.y + v4.z*s4.z + v4.w*s4.w;
        }
        qout[(size_t)(nb + sg) * H_ + o] = aq + bq[o];
        kout[(size_t)(nb + sg) * H_ + o] = ak + bk[o];
        vout[(size_t)(nb + sg) * H_ + o] = av + bv[o];
    }
}

// Cross-asset attention: one block per (b, m) query row, 256 threads. fp32 out.
__global__ __launch_bounds__(256, 4)
void caan(const float* __restrict__ qb, const float* __restrict__ kb,
          const float* __restrict__ vb, const float* __restrict__ ww,
          const float* __restrict__ bw, float* __restrict__ out)
{
    __shared__ alignas(16) float qs[H_];
    __shared__ alignas(16) float sc[512];
    __shared__ alignas(16) float red[8];
    __shared__ alignas(16) float pv[2][H_];

    const int n   = blockIdx.x;
    const int b   = n >> 9;
    const int tid = threadIdx.x;

    if (tid < H_) qs[tid] = qb[n * H_ + tid];
    __syncthreads();

    const float scale = 0.08838834764831845f;  // 1/sqrt(128)
    float s0raw = 0.f, s1raw = 0.f;
    #pragma unroll
    for (int r = 0; r < 2; ++r) {
        const int j = tid + r * 256;
        const float4* kp = (const float4*)(kb + (size_t)(b * 512 + j) * H_);
        const float4* qp = (const float4*)qs;
        float c0=0.f,c1=0.f,c2=0.f,c3=0.f;
        #pragma unroll
        for (int i = 0; i < 32; ++i) {
            float4 kv = kp[i], qv = qp[i];
            c0 += kv.x*qv.x; c1 += kv.y*qv.y; c2 += kv.z*qv.z; c3 += kv.w*qv.w;
        }
        float sres = ((c0 + c1) + (c2 + c3)) * scale;
        if (r == 0) s0raw = sres; else s1raw = sres;
    }

    float m = fmaxf(s0raw, s1raw);
    #pragma unroll
    for (int off = 1; off < 64; off <<= 1) m = fmaxf(m, __shfl_xor(m, off));
    if ((tid & 63) == 0) red[tid >> 6] = m;
    __syncthreads();
    m = fmaxf(fmaxf(red[0], red[1]), fmaxf(red[2], red[3]));
    float e0 = __expf(s0raw - m), e1 = __expf(s1raw - m);
    sc[tid] = e0; sc[tid + 256] = e1;
    float lsum = e0 + e1;
    #pragma unroll
    for (int off = 1; off < 64; off <<= 1) lsum += __shfl_xor(lsum, off);
    if ((tid & 63) == 0) red[4 + (tid >> 6)] = lsum;
    __syncthreads();
    const float inv = 1.0f / ((red[4] + red[5]) + (red[6] + red[7]));

    const int o  = tid & (H_ - 1);
    const int jh = tid >> 7;
    const float* vp = vb + (size_t)(b * 512 + jh * 256) * H_ + o;
    float a0=0.f,a1=0.f,a2=0.f,a3=0.f;
    for (int j = 0; j < 256; j += 4) {
        a0 += sc[jh*256 + j + 0] * vp[(size_t)(j + 0) * H_];
        a1 += sc[jh*256 + j + 1] * vp[(size_t)(j + 1) * H_];
        a2 += sc[jh*256 + j + 2] * vp[(size_t)(j + 2) * H_];
        a3 += sc[jh*256 + j + 3] * vp[(size_t)(j + 3) * H_];
    }
    pv[jh][o] = (a0 + a1) + (a2 + a3);
    __syncthreads();
    if (tid < H_) {
        float s = (pv[0][tid] + pv[1][tid]) * inv * ww[tid];
        s += __shfl_xor(s, 1);  s += __shfl_xor(s, 2);  s += __shfl_xor(s, 4);
        s += __shfl_xor(s, 8);  s += __shfl_xor(s, 16); s += __shfl_xor(s, 32);
        if ((tid & 63) == 0) red[tid >> 6] = s;
    }
    __syncthreads();
    if (tid == 0) out[n] = red[0] + red[1] + bw[0];
}

extern "C" void kernel_launch(void* const* d_in, const int* in_sizes, int n_in,
                              void* d_out, int out_size, void* d_ws, size_t ws_size,
                              hipStream_t stream)
{
    const float* x    = (const float*)d_in[0];
    const float* W_ih = (const float*)d_in[1];
    const float* W_hh = (const float*)d_in[2];
    const float* b_ih = (const float*)d_in[3];
    const float* b_hh = (const float*)d_in[4];
    const float* w1   = (const float*)d_in[5];
    const float* b1   = (const float*)d_in[6];
    const float* w2   = (const float*)d_in[7];
    const float* b2   = (const float*)d_in[8];
    const float* wa   = (const float*)d_in[9];
    const float* ba   = (const float*)d_in[10];
    const float* wq   = (const float*)d_in[11];
    const float* bq   = (const float*)d_in[12];
    const float* wk   = (const float*)d_in[13];
    const float* bk   = (const float*)d_in[14];
    const float* wv   = (const float*)d_in[15];
    const float* bv   = (const float*)d_in[16];
    const float* ww   = (const float*)d_in[17];
    const float* bw   = (const float*)d_in[18];

    float* ws   = (float*)d_ws;
    float* qbuf = ws;                              // 1024*128 f32
    float* kbuf = ws + (size_t)NSEQ_ * H_;
    float* vbuf = ws + (size_t)2 * NSEQ_ * H_;
    ushort* rep = (ushort*)(ws + (size_t)3 * NSEQ_ * H_);        // 16 MB fp16

    alphastock_main<<<NBLK_, 512, 0, stream>>>(x, W_ih, W_hh, b_ih, b_hh,
                                               w1, b1, w2, b2, wa, ba,
                                               wq, bq, wk, bk, wv, bv,
                                               rep, qbuf, kbuf, vbuf);
    caan<<<NSEQ_, 256, 0, stream>>>(qbuf, kbuf, vbuf, ww, bw, (float*)d_out);
}

// Round 12
// 174.030 us; speedup vs baseline: 1.8454x; 1.2438x over previous
//
#include <hip/hip_runtime.h>
#include <hip/hip_bf16.h>

#define DEVI __device__ __forceinline__

typedef float f32x4 __attribute__((ext_vector_type(4)));
typedef short s16x8 __attribute__((ext_vector_type(8)));

constexpr int T_ = 64;    // window
constexpr int F_ = 16;    // features
constexpr int H_ = 128;   // hidden
constexpr int NSEQ_ = 1024;
constexpr int NB_ = 4;    // sequences per block (MFMA N cols 4..15 don't-care)
constexpr int NBLK_ = NSEQ_ / NB_;  // 256 blocks -> every CU gets work

DEVI float sigmoidf_(float x) { return 1.0f / (1.0f + __expf(-x)); }
DEVI float tanhf_(float x) {
    float a = fabsf(x);
    float e = __expf(-2.0f * a);
    return copysignf((1.0f - e) / (1.0f + e), x);
}
DEVI ushort f2h(float f) {              // fp32 -> fp16 bits
    _Float16 h = (_Float16)f;
    ushort b; __builtin_memcpy(&b, &h, 2); return b;
}
DEVI float h2f(ushort b) {
    _Float16 h; __builtin_memcpy(&h, &b, 2); return (float)h;
}

#define MFMA16(A,B,C) __builtin_amdgcn_mfma_f32_16x16x32_f16((A),(B),(C),0,0,0)

// LDS pool, phase-aliased (52768 B):
//  recurrence: xh ushort[4][1032] @0 (8256B)  [x fp16, 4 real seqs]
//              hA @8320 (5376B), hB @13696 (5376B)   [h fp16 ping-pong, 16 rows]
//  epilogue (recurrence regions dead):
//              w1h ushort[128][140] @0 (35840B)
//              a2s  float[16][128]  @35840
//              logitb float[16][64] @44032
//              alph   float[16][64] @48128
//              wab    float[132]    @52224
constexpr int XSTR = 1032;
constexpr int HSTR = 168;   // f16 per h row (336 B)
constexpr int OFF_HA  = 8320, OFF_HB = 13696;
constexpr int OFF_A2S = 35840, OFF_LOG = 44032, OFF_ALPH = 48128, OFF_WAB = 52224;
constexpr int POOL_BYTES = 52768;

__global__ __launch_bounds__(512, 2)
void alphastock_main(const float* __restrict__ x,
                     const float* __restrict__ W_ih, const float* __restrict__ W_hh,
                     const float* __restrict__ b_ih, const float* __restrict__ b_hh,
                     const float* __restrict__ w1, const float* __restrict__ b1,
                     const float* __restrict__ w2, const float* __restrict__ b2,
                     const float* __restrict__ wa, const float* __restrict__ ba,
                     const float* __restrict__ wq, const float* __restrict__ bq,
                     const float* __restrict__ wk, const float* __restrict__ bk,
                     const float* __restrict__ wvm, const float* __restrict__ bv,
                     ushort* __restrict__ rep,   // [1024][64][128] fp16 ws
                     float* __restrict__ qout, float* __restrict__ kout,
                     float* __restrict__ vout)
{
    __shared__ alignas(16) char pool_[POOL_BYTES];
    ushort* xh    = (ushort*)pool_;
    ushort* hA    = (ushort*)(pool_ + OFF_HA);
    ushort* hB    = (ushort*)(pool_ + OFF_HB);
    ushort* w1h   = (ushort*)pool_;                    // epilogue alias
    float*  a2s   = (float*)(pool_ + OFF_A2S);
    float*  logitb= (float*)(pool_ + OFF_LOG);
    float*  alph  = (float*)(pool_ + OFF_ALPH);
    float*  wab   = (float*)(pool_ + OFF_WAB);

    const int tid  = threadIdx.x;
    const int wv   = tid >> 6;        // wave 0..7
    const int lane = tid & 63;
    const int lN   = lane & 15;       // frag col (seq; real 0..3) / A-row
    const int lK   = lane >> 4;       // k-group 0..3
    const int nb   = blockIdx.x * NB_;

    // ---- prologue: zero BOTH h buffers; stage x (4 seqs) -> LDS fp16 ----
    for (int i = tid; i < 10752 / 4; i += 512)
        ((unsigned*)(pool_ + OFF_HA))[i] = 0;          // hA + hB (contiguous)
    for (int idx = tid; idx < NB_ * T_ * F_; idx += 512) {   // 4096
        int s = idx >> 10, rem = idx & 1023;                 // rem = t*16+f
        xh[s * XSTR + rem] = f2h(x[(size_t)(nb + s) * 1024 + rem]);
    }

    // ---- A-frags Whh fp16: row ra = 128g + 16wv + lN; k = ks*32 + lK*8 + i
    s16x8 wf[4][4];
    #pragma unroll
    for (int g = 0; g < 4; ++g) {
        const int ra = 128 * g + 16 * wv + lN;
        #pragma unroll
        for (int ks = 0; ks < 4; ++ks) {
            const float4* p = (const float4*)(W_hh + (size_t)ra * 128 + ks * 32 + lK * 8);
            float4 v0 = p[0], v1 = p[1];
            float w[8] = {v0.x,v0.y,v0.z,v0.w, v1.x,v1.y,v1.z,v1.w};
            #pragma unroll
            for (int i = 0; i < 8; ++i) wf[g][ks][i] = (short)f2h(w[i]);
        }
    }
    // Wih fp16 frags: K=16 padded to 32; lanes lK>=2 get zero A.
    s16x8 wif[4];
    #pragma unroll
    for (int g = 0; g < 4; ++g) {
        const int ra = 128 * g + 16 * wv + lN;
        const float4* p = (const float4*)(W_ih + (size_t)ra * 16 + (lK & 1) * 8);
        float4 v0 = p[0], v1 = p[1];
        float w[8] = {v0.x,v0.y,v0.z,v0.w, v1.x,v1.y,v1.z,v1.w};
        #pragma unroll
        for (int i = 0; i < 8; ++i)
            wif[g][i] = (short)((lK < 2) ? f2h(w[i]) : 0);
    }
    // bias folded into acc init: rows 128g + 16wv + 4lK + r
    f32x4 bias4[4];
    #pragma unroll
    for (int g = 0; g < 4; ++g)
        #pragma unroll
        for (int r = 0; r < 4; ++r) {
            int rr = 128 * g + 16 * wv + 4 * lK + r;
            bias4[g][r] = b_ih[rr] + b_hh[rr];
        }
    __syncthreads();

    // ---- recurrent loop ----
    // After MFMA, redistribute so lane L owns cell (j_local = L>>2, s = L&3):
    // source lane (L&3) + 16*(L>>4), register r = (L>>2)&3. One cell update
    // per lane (was 4, with 4x duplication) -> 4x less transcendental work.
    const int hoff = lN * HSTR;
    const ushort* xrow = xh + (lN & 3) * XSTR + (lK & 1) * 8;
    const int srcLane = (lane & 3) + 16 * (lane >> 4);
    const int rsel    = (lane >> 2) & 3;
    const int jloc    = lane >> 2;          // 0..15
    const int sloc    = lane & 3;           // 0..3
    const int hwoff   = sloc * HSTR + 16 * wv + jloc;   // h write slot (2B)
    ushort* repL = rep + ((size_t)(nb + sloc) * T_) * H_ + 16 * wv + jloc;
    float cst = 0.f;
    #pragma unroll 1
    for (int tb = 0; tb < 16; ++tb) {
        s16x8 bx0 = *(const s16x8*)(xrow + (4 * tb + 0) * 16);
        s16x8 bx1 = *(const s16x8*)(xrow + (4 * tb + 1) * 16);
        s16x8 bx2 = *(const s16x8*)(xrow + (4 * tb + 2) * 16);
        s16x8 bx3 = *(const s16x8*)(xrow + (4 * tb + 3) * 16);
        #pragma unroll
        for (int u = 0; u < 4; ++u) {
            const int t = 4 * tb + u;
            s16x8 bx = (u == 0) ? bx0 : (u == 1) ? bx1 : (u == 2) ? bx2 : bx3;

            f32x4 acc0 = MFMA16(wif[0], bx, bias4[0]);
            f32x4 acc1 = MFMA16(wif[1], bx, bias4[1]);
            f32x4 acc2 = MFMA16(wif[2], bx, bias4[2]);
            f32x4 acc3 = MFMA16(wif[3], bx, bias4[3]);

            const ushort* hh = (u & 1) ? hB : hA;     // compile-time select
            #pragma unroll
            for (int ks = 0; ks < 4; ++ks) {
                s16x8 bh = *(const s16x8*)(hh + hoff + ks * 32 + lK * 8);
                acc0 = MFMA16(wf[0][ks], bh, acc0);
                acc1 = MFMA16(wf[1][ks], bh, acc1);
                acc2 = MFMA16(wf[2][ks], bh, acc2);
                acc3 = MFMA16(wf[3][ks], bh, acc3);
            }

            // redistribute the 4 gate values for this lane's (jloc, sloc)
            float t0, t1, t2, t3, gi, gf, gg, go;
            t0 = __shfl(acc0[0], srcLane); t1 = __shfl(acc0[1], srcLane);
            t2 = __shfl(acc0[2], srcLane); t3 = __shfl(acc0[3], srcLane);
            gi = (rsel < 2) ? (rsel ? t1 : t0) : ((rsel == 2) ? t2 : t3);
            t0 = __shfl(acc1[0], srcLane); t1 = __shfl(acc1[1], srcLane);
            t2 = __shfl(acc1[2], srcLane); t3 = __shfl(acc1[3], srcLane);
            gf = (rsel < 2) ? (rsel ? t1 : t0) : ((rsel == 2) ? t2 : t3);
            t0 = __shfl(acc2[0], srcLane); t1 = __shfl(acc2[1], srcLane);
            t2 = __shfl(acc2[2], srcLane); t3 = __shfl(acc2[3], srcLane);
            gg = (rsel < 2) ? (rsel ? t1 : t0) : ((rsel == 2) ? t2 : t3);
            t0 = __shfl(acc3[0], srcLane); t1 = __shfl(acc3[1], srcLane);
            t2 = __shfl(acc3[2], srcLane); t3 = __shfl(acc3[3], srcLane);
            go = (rsel < 2) ? (rsel ? t1 : t0) : ((rsel == 2) ? t2 : t3);

            // ONE cell update per lane
            float ii = sigmoidf_(gi);
            float ff = sigmoidf_(gf);
            float gt = tanhf_(gg);
            float oo = sigmoidf_(go);
            float c  = ff * cst + ii * gt;
            cst = c;
            ushort hb = f2h(oo * tanhf_(c));

            ushort* hw = (u & 1) ? hA : hB;           // write the OTHER buffer
            hw[hwoff] = hb;                           // 2B LDS write
            repL[(size_t)t * H_] = hb;                // 2B global (32B segments)
            __syncthreads();
        }
    }

    // ================= epilogue (4 seqs in this block) =================
    // E0: stage w1 (fp16, stride 140) + wa/ba  (recurrence LDS dead)
    for (int idx = tid; idx < 128 * 128; idx += 512) {
        int o = idx >> 7, k = idx & 127;
        w1h[o * 140 + k] = f2h(w1[idx]);
    }
    if (tid < 128) wab[tid] = wa[tid];
    if (tid == 128) wab[128] = ba[0];
    __syncthreads();

    // E1: a2[s][o] = h63 @ w2^T + b1 + b2  (wave 0; A rows >=4 dup of row&3)
    if (wv == 0) {
        s16x8 ar[4];
        #pragma unroll
        for (int ks = 0; ks < 4; ++ks)
            ar[ks] = *(const s16x8*)(rep + ((size_t)(nb + (lN & 3)) * T_ + 63) * H_ + ks * 32 + lK * 8);
        #pragma unroll
        for (int nt = 0; nt < 8; ++nt) {
            f32x4 acc = {0.f,0.f,0.f,0.f};
            const int o = 16 * nt + lN;
            #pragma unroll
            for (int ks = 0; ks < 4; ++ks) {
                const float4* p = (const float4*)(w2 + (size_t)o * 128 + ks * 32 + lK * 8);
                float4 v0 = p[0], v1 = p[1];
                s16x8 bb;
                bb[0]=(short)f2h(v0.x); bb[1]=(short)f2h(v0.y); bb[2]=(short)f2h(v0.z); bb[3]=(short)f2h(v0.w);
                bb[4]=(short)f2h(v1.x); bb[5]=(short)f2h(v1.y); bb[6]=(short)f2h(v1.z); bb[7]=(short)f2h(v1.w);
                acc = MFMA16(ar[ks], bb, acc);
            }
            float bb12 = b1[o] + b2[o];
            #pragma unroll
            for (int r = 0; r < 4; ++r)
                a2s[(4 * lK + r) * 128 + o] = acc[r] + bb12;   // seq = 4lK+r
        }
    }
    __syncthreads();

    // E2: logits[t] = sum_o wa[o]*tanh((rep @ w1^T)[t][o] + a2[o])
    // 2 waves per seq: seq = wv>>1, mt = (wv&1)*2 + mtl
    {
        const int seq = wv >> 1;
        #pragma unroll 1
        for (int mtl = 0; mtl < 2; ++mtl) {
            const int mt = (wv & 1) * 2 + mtl;
            s16x8 ar[4];
            #pragma unroll
            for (int ks = 0; ks < 4; ++ks)
                ar[ks] = *(const s16x8*)(rep + ((size_t)(nb + seq) * T_ + 16 * mt + lN) * H_ + ks * 32 + lK * 8);
            float part[4] = {0.f,0.f,0.f,0.f};
            #pragma unroll
            for (int nt = 0; nt < 8; ++nt) {
                f32x4 acc = {0.f,0.f,0.f,0.f};
                #pragma unroll
                for (int ks = 0; ks < 4; ++ks)
                    acc = MFMA16(ar[ks],
                                 *(const s16x8*)(w1h + (lN + 16 * nt) * 140 + ks * 32 + lK * 8),
                                 acc);
                const int o = lN + 16 * nt;
                const float wao = wab[o];
                const float a2o = a2s[seq * 128 + o];
                #pragma unroll
                for (int r = 0; r < 4; ++r)
                    part[r] += wao * tanhf_(acc[r] + a2o);
            }
            #pragma unroll
            for (int r = 0; r < 4; ++r) {
                part[r] += __shfl_xor(part[r], 1);
                part[r] += __shfl_xor(part[r], 2);
                part[r] += __shfl_xor(part[r], 4);
                part[r] += __shfl_xor(part[r], 8);
            }
            if (lN == 0) {
                float4 st; st.x = part[0]; st.y = part[1]; st.z = part[2]; st.w = part[3];
                *(float4*)(logitb + seq * 64 + 16 * mt + 4 * lK) = st;  // t = 16mt+4lK+r
            }
        }
    }
    __syncthreads();

    // E3: softmax over 64 logits, seq = wv (waves 0..3)
    if (wv < NB_) {
        const int seq = wv;
        float vl = logitb[seq * 64 + lane] + wab[128];
        float m = vl;
        #pragma unroll
        for (int off = 1; off < 64; off <<= 1) m = fmaxf(m, __shfl_xor(m, off));
        float e = __expf(vl - m);
        float ss = e;
        #pragma unroll
        for (int off = 1; off < 64; off <<= 1) ss += __shfl_xor(ss, off);
        alph[seq * 64 + lane] = e / ss;
    }
    __syncthreads();

    // E4: stock_rep[s][h] = sum_t alpha * rep  (fp32, into a2s alias)
    {
        const int s = tid >> 7, o = tid & 127;     // 1 element per thread
        float acc = 0.f;
        const ushort* rp = rep + (size_t)(nb + s) * T_ * H_ + o;
        #pragma unroll 8
        for (int t = 0; t < T_; ++t)
            acc += alph[s * 64 + t] * h2f(rp[(size_t)t * H_]);
        __syncthreads();                           // a2s readers (E2) done
        a2s[s * 128 + o] = acc;
    }
    __syncthreads();

    // E5: q,k,v = sr @ W^T + b  (fp32 VALU; one seq per thread-group)
    {
        const float* sr = a2s;
        const int o = tid & 127, sg = tid >> 7;    // sg = seq 0..3
        float aq = 0.f, ak = 0.f, av = 0.f;
        for (int k = 0; k < 128; k += 4) {
            float4 q4 = *(const float4*)(wq  + (size_t)o * 128 + k);
            float4 k4 = *(const float4*)(wk  + (size_t)o * 128 + k);
            float4 v4 = *(const float4*)(wvm + (size_t)o * 128 + k);
            float4 s4 = *(const float4*)(sr + sg * 128 + k);
            aq += q4.x*s4.x + q4.y*s4.y + q4.z*s4.z + q4.w*s4.w;
            ak += k4.x*s4.x + k4.y*s4.y + k4.z*s4.z + k4.w*s4.w;
            av += v4.x*s4.x + v4.y*s4.y + v4.z*s4.z + v4.w*s4.w;
        }
        qout[(size_t)(nb + sg) * H_ + o] = aq + bq[o];
        kout[(size_t)(nb + sg) * H_ + o] = ak + bk[o];
        vout[(size_t)(nb + sg) * H_ + o] = av + bv[o];
    }
}

// Cross-asset attention: one block per (b, m) query row, 256 threads. fp32 out.
__global__ __launch_bounds__(256, 4)
void caan(const float* __restrict__ qb, const float* __restrict__ kb,
          const float* __restrict__ vb, const float* __restrict__ ww,
          const float* __restrict__ bw, float* __restrict__ out)
{
    __shared__ alignas(16) float qs[H_];
    __shared__ alignas(16) float sc[512];
    __shared__ alignas(16) float red[8];
    __shared__ alignas(16) float pv[2][H_];

    const int n   = blockIdx.x;
    const int b   = n >> 9;
    const int tid = threadIdx.x;

    if (tid < H_) qs[tid] = qb[n * H_ + tid];
    __syncthreads();

    const float scale = 0.08838834764831845f;  // 1/sqrt(128)
    float s0raw = 0.f, s1raw = 0.f;
    #pragma unroll
    for (int r = 0; r < 2; ++r) {
        const int j = tid + r * 256;
        const float4* kp = (const float4*)(kb + (size_t)(b * 512 + j) * H_);
        const float4* qp = (const float4*)qs;
        float c0=0.f,c1=0.f,c2=0.f,c3=0.f;
        #pragma unroll
        for (int i = 0; i < 32; ++i) {
            float4 kv = kp[i], qv = qp[i];
            c0 += kv.x*qv.x; c1 += kv.y*qv.y; c2 += kv.z*qv.z; c3 += kv.w*qv.w;
        }
        float sres = ((c0 + c1) + (c2 + c3)) * scale;
        if (r == 0) s0raw = sres; else s1raw = sres;
    }

    float m = fmaxf(s0raw, s1raw);
    #pragma unroll
    for (int off = 1; off < 64; off <<= 1) m = fmaxf(m, __shfl_xor(m, off));
    if ((tid & 63) == 0) red[tid >> 6] = m;
    __syncthreads();
    m = fmaxf(fmaxf(red[0], red[1]), fmaxf(red[2], red[3]));
    float e0 = __expf(s0raw - m), e1 = __expf(s1raw - m);
    sc[tid] = e0; sc[tid + 256] = e1;
    float lsum = e0 + e1;
    #pragma unroll
    for (int off = 1; off < 64; off <<= 1) lsum += __shfl_xor(lsum, off);
    if ((tid & 63) == 0) red[4 + (tid >> 6)] = lsum;
    __syncthreads();
    const float inv = 1.0f / ((red[4] + red[5]) + (red[6] + red[7]));

    const int o  = tid & (H_ - 1);
    const int jh = tid >> 7;
    const float* vp = vb + (size_t)(b * 512 + jh * 256) * H_ + o;
    float a0=0.f,a1=0.f,a2=0.f,a3=0.f;
    for (int j = 0; j < 256; j += 4) {
        a0 += sc[jh*256 + j + 0] * vp[(size_t)(j + 0) * H_];
        a1 += sc[jh*256 + j + 1] * vp[(size_t)(j + 1) * H_];
        a2 += sc[jh*256 + j + 2] * vp[(size_t)(j + 2) * H_];
        a3 += sc[jh*256 + j + 3] * vp[(size_t)(j + 3) * H_];
    }
    pv[jh][o] = (a0 + a1) + (a2 + a3);
    __syncthreads();
    if (tid < H_) {
        float s = (pv[0][tid] + pv[1][tid]) * inv * ww[tid];
        s += __shfl_xor(s, 1);  s += __shfl_xor(s, 2);  s += __shfl_xor(s, 4);
        s += __shfl_xor(s, 8);  s += __shfl_xor(s, 16); s += __shfl_xor(s, 32);
        if ((tid & 63) == 0) red[tid >> 6] = s;
    }
    __syncthreads();
    if (tid == 0) out[n] = red[0] + red[1] + bw[0];
}

extern "C" void kernel_launch(void* const* d_in, const int* in_sizes, int n_in,
                              void* d_out, int out_size, void* d_ws, size_t ws_size,
                              hipStream_t stream)
{
    const float* x    = (const float*)d_in[0];
    const float* W_ih = (const float*)d_in[1];
    const float* W_hh = (const float*)d_in[2];
    const float* b_ih = (const float*)d_in[3];
    const float* b_hh = (const float*)d_in[4];
    const float* w1   = (const float*)d_in[5];
    const float* b1   = (const float*)d_in[6];
    const float* w2   = (const float*)d_in[7];
    const float* b2   = (const float*)d_in[8];
    const float* wa   = (const float*)d_in[9];
    const float* ba   = (const float*)d_in[10];
    const float* wq   = (const float*)d_in[11];
    const float* bq   = (const float*)d_in[12];
    const float* wk   = (const float*)d_in[13];
    const float* bk   = (const float*)d_in[14];
    const float* wv   = (const float*)d_in[15];
    const float* bv   = (const float*)d_in[16];
    const float* ww   = (const float*)d_in[17];
    const float* bw   = (const float*)d_in[18];

    float* ws   = (float*)d_ws;
    float* qbuf = ws;                              // 1024*128 f32
    float* kbuf = ws + (size_t)NSEQ_ * H_;
    float* vbuf = ws + (size_t)2 * NSEQ_ * H_;
    ushort* rep = (ushort*)(ws + (size_t)3 * NSEQ_ * H_);        // 16 MB fp16

    alphastock_main<<<NBLK_, 512, 0, stream>>>(x, W_ih, W_hh, b_ih, b_hh,
                                               w1, b1, w2, b2, wa, ba,
                                               wq, bq, wk, bk, wv, bv,
                                               rep, qbuf, kbuf, vbuf);
    caan<<<NSEQ_, 256, 0, stream>>>(qbuf, kbuf, vbuf, ww, bw, (float*)d_out);
}